// Round 3
// baseline (886.373 us; speedup 1.0000x reference)
//
#include <hip/hip_runtime.h>

#define S_LEN 2048
#define B_SZ 2
#define D_DIM 1024
#define H_HEADS 16
#define DK_DIM 64
#define E_EXP 8
#define F_DIM 4096
#define T_TOK 4096   // S*B

typedef unsigned short ush;
typedef __bf16 bf16x8 __attribute__((ext_vector_type(8)));
typedef float f32x4 __attribute__((ext_vector_type(4)));

__device__ __forceinline__ ush f2bf(float f) {
  union { __bf16 h; ush u; } cv;
  cv.h = (__bf16)f;
  return cv.u;
}

__device__ __forceinline__ float bf2f(ush u) {
  union { unsigned int i; float f; } cv;
  cv.i = ((unsigned int)u) << 16;
  return cv.f;
}

// split v into hi + lo bf16 (v ~= hi + lo, rel err ~2^-17)
__device__ __forceinline__ void split2(float v, ush& h, ush& l) {
  ush hh = f2bf(v);
  h = hh;
  l = f2bf(v - bf2f(hh));
}

__device__ __forceinline__ void gload16(const void* g, void* l) {
  __builtin_amdgcn_global_load_lds(
      (const __attribute__((address_space(1))) unsigned int*)g,
      (__attribute__((address_space(3))) unsigned int*)l, 16, 0, 0);
}

#define MFMA(a, b, c) __builtin_amdgcn_mfma_f32_16x16x32_bf16(a, b, c, 0, 0, 0)

// ---- DPP 16-lane all-reduce (pure VALU, replaces ds_bpermute shuffles) ----
template <int CTRL>
__device__ __forceinline__ float dpp_mov(float x) {
  return __builtin_bit_cast(float,
      __builtin_amdgcn_update_dpp(0, __builtin_bit_cast(int, x), CTRL, 0xF, 0xF,
                                  true));
}
__device__ __forceinline__ float rmax16(float x) {
  x = fmaxf(x, dpp_mov<0xB1>(x));    // quad_perm xor1
  x = fmaxf(x, dpp_mov<0x4E>(x));    // quad_perm xor2
  x = fmaxf(x, dpp_mov<0x141>(x));   // row_half_mirror
  x = fmaxf(x, dpp_mov<0x140>(x));   // row_mirror
  return x;
}
__device__ __forceinline__ float rsum16(float x) {
  x += dpp_mov<0xB1>(x);
  x += dpp_mov<0x4E>(x);
  x += dpp_mov<0x141>(x);
  x += dpp_mov<0x140>(x);
  return x;
}

// ---------------- LN1: x -> split bf16 z ----------------
__global__ __launch_bounds__(256) void ln1_split(const float* __restrict__ x,
    const float* __restrict__ g, const float* __restrict__ b,
    ush* __restrict__ zh, ush* __restrict__ zl) {
  int t = blockIdx.x;
  float4 v = ((const float4*)(x + (size_t)t * D_DIM))[threadIdx.x];
  float s = v.x + v.y + v.z + v.w;
  float s2 = v.x * v.x + v.y * v.y + v.z * v.z + v.w * v.w;
#pragma unroll
  for (int off = 32; off > 0; off >>= 1) {
    s += __shfl_down(s, off);
    s2 += __shfl_down(s2, off);
  }
  __shared__ float red[8];
  int wid = threadIdx.x >> 6;
  if ((threadIdx.x & 63) == 0) { red[wid] = s; red[4 + wid] = s2; }
  __syncthreads();
  float sum = red[0] + red[1] + red[2] + red[3];
  float sq = red[4] + red[5] + red[6] + red[7];
  float mu = sum * (1.0f / D_DIM);
  float var = sq * (1.0f / D_DIM) - mu * mu;
  float rstd = rsqrtf(var + 1e-5f);
  float4 gg = ((const float4*)g)[threadIdx.x];
  float4 bb = ((const float4*)b)[threadIdx.x];
  float o[4];
  o[0] = (v.x - mu) * rstd * gg.x + bb.x;
  o[1] = (v.y - mu) * rstd * gg.y + bb.y;
  o[2] = (v.z - mu) * rstd * gg.z + bb.z;
  o[3] = (v.w - mu) * rstd * gg.w + bb.w;
  ushort4 uh, ul;
  split2(o[0], uh.x, ul.x); split2(o[1], uh.y, ul.y);
  split2(o[2], uh.z, ul.z); split2(o[3], uh.w, ul.w);
  *(ushort4*)(zh + (size_t)t * D_DIM + threadIdx.x * 4) = uh;
  *(ushort4*)(zl + (size_t)t * D_DIM + threadIdx.x * 4) = ul;
}

// ------------- transpose fp32 [R][C] -> split bf16 [C][R] -------------
__global__ __launch_bounds__(256) void transpose_split(const float* __restrict__ in,
    ush* __restrict__ outh, ush* __restrict__ outl, int R, int C) {
  __shared__ float tile[32][33];
  int c0 = blockIdx.x * 32, r0 = blockIdx.y * 32;
  int tx = threadIdx.x & 31, ty = threadIdx.x >> 5;
#pragma unroll
  for (int i = 0; i < 4; i++)
    tile[ty + i * 8][tx] = in[(size_t)(r0 + ty + i * 8) * C + c0 + tx];
  __syncthreads();
#pragma unroll
  for (int i = 0; i < 4; i++) {
    float v = tile[tx][ty + i * 8];
    ush h, l;
    split2(v, h, l);
    size_t idx = (size_t)(c0 + ty + i * 8) * R + r0 + tx;
    outh[idx] = h;
    outl[idx] = l;
  }
}

// ------------- transpose fp32 [E][R][C] -> plain bf16 [E][C][R] -------------
__global__ __launch_bounds__(256) void transpose_bf16(const float* __restrict__ in,
    ush* __restrict__ out, int R, int C) {
  __shared__ float tile[32][33];
  int e = blockIdx.z;
  const float* ip = in + (size_t)e * R * C;
  ush* op = out + (size_t)e * R * C;
  int c0 = blockIdx.x * 32, r0 = blockIdx.y * 32;
  int tx = threadIdx.x & 31, ty = threadIdx.x >> 5;
#pragma unroll
  for (int i = 0; i < 4; i++)
    tile[ty + i * 8][tx] = ip[(size_t)(r0 + ty + i * 8) * C + c0 + tx];
  __syncthreads();
#pragma unroll
  for (int i = 0; i < 4; i++)
    op[(size_t)(c0 + ty + i * 8) * R + r0 + tx] = f2bf(tile[tx][ty + i * 8]);
}

// ------- split-bf16 GEMM core: 128x128 tile, BK=64, XOR-swizzled LDS -------
// Staging: source chunk pre-swizzled ((c ^ row&7)), LDS dst linear (gload16
// requirement); reads XOR the chunk back. Same scheme as attn (0 conflicts).
__device__ __forceinline__ void split_gemm(const ush* __restrict__ Ah,
    const ush* __restrict__ Al, int lda, const ush* __restrict__ Bh,
    const ush* __restrict__ Bl, int ldb, int K, int tid, f32x4 acc[4][4],
    ush (*Ash)[64], ush (*Asl)[64], ush (*Bsh)[64], ush (*Bsl)[64]) {
  int lane = tid & 63, w = tid >> 6, quad = lane >> 4, ln15 = lane & 15;
  int srow = tid >> 3, pcol = (tid & 7) * 8;
  int scol = ((tid & 7) ^ (srow & 7)) * 8;   // swizzled global source chunk
  int sw = ln15 & 7;                         // frag-read swizzle key
  int mb = (w >> 1) * 64, nb = (w & 1) * 64;
  for (int kb = 0; kb < K; kb += 64) {
    __syncthreads();
#pragma unroll
    for (int r = 0; r < 4; r++) {
      int rr = r * 32 + srow;
      gload16(Ah + (size_t)rr * lda + kb + scol, &Ash[rr][pcol]);
      gload16(Al + (size_t)rr * lda + kb + scol, &Asl[rr][pcol]);
      gload16(Bh + (size_t)rr * ldb + kb + scol, &Bsh[rr][pcol]);
      gload16(Bl + (size_t)rr * ldb + kb + scol, &Bsl[rr][pcol]);
    }
    __syncthreads();
#pragma unroll
    for (int kc = 0; kc < 2; kc++) {
      int kof = ((kc * 4 + quad) ^ sw) * 8;
      bf16x8 avh[4], avl[4], bvh[4], bvl[4];
#pragma unroll
      for (int i = 0; i < 4; i++) {
        avh[i] = *(const bf16x8*)&Ash[mb + i * 16 + ln15][kof];
        avl[i] = *(const bf16x8*)&Asl[mb + i * 16 + ln15][kof];
        bvh[i] = *(const bf16x8*)&Bsh[nb + i * 16 + ln15][kof];
        bvl[i] = *(const bf16x8*)&Bsl[nb + i * 16 + ln15][kof];
      }
#pragma unroll
      for (int mi = 0; mi < 4; mi++)
#pragma unroll
        for (int ni = 0; ni < 4; ni++) {
          acc[mi][ni] = MFMA(avh[mi], bvh[ni], acc[mi][ni]);
          acc[mi][ni] = MFMA(avh[mi], bvl[ni], acc[mi][ni]);
          acc[mi][ni] = MFMA(avl[mi], bvh[ni], acc[mi][ni]);
        }
    }
  }
}

// ---------------- QKV: z @ w{q,k,v} + bias -> split bf16 ----------------
__global__ __launch_bounds__(256) void qkv_mfma(const ush* __restrict__ zh,
    const ush* __restrict__ zl, const ush* __restrict__ wT,
    const float* __restrict__ bq, const float* __restrict__ bk,
    const float* __restrict__ bv, ush* __restrict__ qh_, ush* __restrict__ kh_,
    ush* __restrict__ vth_) {
  __shared__ ush Ash[128][64], Asl[128][64], Bsh[128][64], Bsl[128][64];
  int z = blockIdx.z;
  int m0 = blockIdx.x * 128, n0 = blockIdx.y * 128;
  const ush* Bh = wT + (size_t)z * 2097152;
  const ush* Bl = Bh + 1048576;
  const float* bias = (z == 0) ? bq : (z == 1) ? bk : bv;
  ush* outh = (z == 0) ? qh_ : (z == 1) ? kh_ : vth_;
  int tid = threadIdx.x, lane = tid & 63, w = tid >> 6;
  int quad = lane >> 4, ln15 = lane & 15;
  int mb = (w >> 1) * 64, nb = (w & 1) * 64;
  f32x4 acc[4][4] = {};
  split_gemm(zh + (size_t)m0 * D_DIM, zl + (size_t)m0 * D_DIM, D_DIM,
             Bh + (size_t)n0 * D_DIM, Bl + (size_t)n0 * D_DIM, D_DIM, D_DIM,
             tid, acc, Ash, Asl, Bsh, Bsl);
#pragma unroll
  for (int mi = 0; mi < 4; mi++)
#pragma unroll
    for (int reg = 0; reg < 4; reg++) {
      int m = m0 + mb + mi * 16 + quad * 4 + reg;
      int s = m >> 1, b = m & 1;
#pragma unroll
      for (int ni = 0; ni < 4; ni++) {
        int n = n0 + nb + ni * 16 + ln15;
        float val = acc[mi][ni][reg] + bias[n];
        ush hh, ll;
        split2(val, hh, ll);
        int h = n >> 6, dk = n & 63;
        size_t idx;
        if (z < 2) idx = ((size_t)(b * H_HEADS + h) * S_LEN + s) * DK_DIM + dk;
        else       idx = ((size_t)(b * H_HEADS + h) * DK_DIM + dk) * S_LEN + s;
        outh[idx] = hh;
        outh[idx + 4194304] = ll;   // lo buffer is +8 MB after hi
      }
    }
}

// ---------------- Flash attention v3 (unchanged from round 2) ----------------
__global__ __launch_bounds__(256, 2) void attn_mfma(const ush* __restrict__ qh,
    const ush* __restrict__ ql, const ush* __restrict__ kh,
    const ush* __restrict__ kl, const ush* __restrict__ vth,
    const ush* __restrict__ vtl, ush* __restrict__ oh, ush* __restrict__ ol) {
  int bh = blockIdx.y, q0 = blockIdx.x * 128;
  const size_t hoff = (size_t)bh * S_LEN * DK_DIM;
  __shared__ float4 smemv[3072];       // 48 KB
  ush* Ph_ = (ush*)smemv;              // [128][64] bf16 P (wave-private rows)
  ush* Kh_ = (ush*)smemv + 8192;       // [64][64]
  ush* Kl_ = (ush*)smemv + 12288;
  ush* Vh_ = (ush*)smemv + 16384;      // [64][64] (Vt: row=dk, col=key)
  ush* Vl_ = (ush*)smemv + 20480;
  int tid = threadIdx.x, lane = tid & 63, w = tid >> 6;
  int quad = lane >> 4, ln15 = lane & 15;
  int srow = tid >> 3;                 // staging row 0..31
  int schunk = tid & 7;                // LDS dst chunk (fixed by gload16)
  int gch = (schunk ^ (srow & 7)) * 8; // swizzled global source chunk (ush)
  int sw = ln15 & 7;                   // frag-read swizzle key
  // ---- prologue: issue K-tile 0 loads; Q fragments direct from global ----
#pragma unroll
  for (int p = 0; p < 2; p++) {
    int r = p * 32 + srow;
    gload16(kh + hoff + (size_t)r * DK_DIM + gch, Kh_ + r * 64 + schunk * 8);
    gload16(kl + hoff + (size_t)r * DK_DIM + gch, Kl_ + r * 64 + schunk * 8);
  }
  bf16x8 Qf[2][2][2];   // [mi][kc][hi/lo]
#pragma unroll
  for (int mi = 0; mi < 2; mi++)
#pragma unroll
    for (int kc = 0; kc < 2; kc++) {
      size_t qidx = hoff + (size_t)(q0 + w * 32 + mi * 16 + ln15) * DK_DIM +
                    (kc * 4 + quad) * 8;
      Qf[mi][kc][0] = *(const bf16x8*)(qh + qidx);
      Qf[mi][kc][1] = *(const bf16x8*)(ql + qidx);
    }
  f32x4 Oacc[2][4] = {};
  float m_i[2][4], l_i[2][4];
#pragma unroll
  for (int mi = 0; mi < 2; mi++)
#pragma unroll
    for (int r = 0; r < 4; r++) { m_i[mi][r] = -3e38f; l_i[mi][r] = 0.f; }
  const float cs = 0.18033688f;        // 0.125 * log2(e): exp2-domain softmax
  __syncthreads();                     // K0 landed
  for (int kt = 0; kt < S_LEN / 64; kt++) {
    // ---- phase A: issue V(kt) loads; QK^T; softmax; store P ----
#pragma unroll
    for (int p = 0; p < 2; p++) {
      int r = p * 32 + srow;
      gload16(vth + hoff + (size_t)r * S_LEN + kt * 64 + gch,
              Vh_ + r * 64 + schunk * 8);
      gload16(vtl + hoff + (size_t)r * S_LEN + kt * 64 + gch,
              Vl_ + r * 64 + schunk * 8);
    }
    f32x4 S[2][4] = {};
#pragma unroll
    for (int kc = 0; kc < 2; kc++) {
      int ch = ((kc * 4 + quad) ^ sw) * 8;
      bf16x8 bkh[4], bkl[4];
#pragma unroll
      for (int ni = 0; ni < 4; ni++) {
        int row = ni * 16 + ln15;
        bkh[ni] = *(const bf16x8*)(Kh_ + row * 64 + ch);
        bkl[ni] = *(const bf16x8*)(Kl_ + row * 64 + ch);
      }
      __builtin_amdgcn_s_setprio(1);
#pragma unroll
      for (int mi = 0; mi < 2; mi++)
#pragma unroll
        for (int ni = 0; ni < 4; ni++) {
          S[mi][ni] = MFMA(Qf[mi][kc][0], bkh[ni], S[mi][ni]);
          S[mi][ni] = MFMA(Qf[mi][kc][0], bkl[ni], S[mi][ni]);
          S[mi][ni] = MFMA(Qf[mi][kc][1], bkh[ni], S[mi][ni]);
        }
      __builtin_amdgcn_s_setprio(0);
    }
    // ---- online softmax: row max via DPP (raw units) ----
    float mt[2][4];
#pragma unroll
    for (int mi = 0; mi < 2; mi++)
#pragma unroll
      for (int reg = 0; reg < 4; reg++) {
        float m = fmaxf(fmaxf(S[mi][0][reg], S[mi][1][reg]),
                        fmaxf(S[mi][2][reg], S[mi][3][reg]));
        mt[mi][reg] = rmax16(m);
      }
    // ---- deferred-max rescale (T13) ----
    float growth = -3e38f;
#pragma unroll
    for (int mi = 0; mi < 2; mi++)
#pragma unroll
      for (int reg = 0; reg < 4; reg++)
        growth = fmaxf(growth, mt[mi][reg] - m_i[mi][reg]);
    if (__any(growth > 44.3614195f)) {   // 8 / cs  =>  p bounded by 2^8
#pragma unroll
      for (int mi = 0; mi < 2; mi++)
#pragma unroll
        for (int reg = 0; reg < 4; reg++) {
          float mnew = fmaxf(m_i[mi][reg], mt[mi][reg]);
          float a = __builtin_amdgcn_exp2f(cs * (m_i[mi][reg] - mnew));
          m_i[mi][reg] = mnew;
          l_i[mi][reg] *= a;
#pragma unroll
          for (int ni = 0; ni < 4; ni++) Oacc[mi][ni][reg] *= a;
        }
    }
    float ncm[2][4], ls[2][4] = {};
#pragma unroll
    for (int mi = 0; mi < 2; mi++)
#pragma unroll
      for (int reg = 0; reg < 4; reg++) ncm[mi][reg] = cs * m_i[mi][reg];
#pragma unroll
    for (int mi = 0; mi < 2; mi++)
#pragma unroll
      for (int ni = 0; ni < 4; ni++)
#pragma unroll
        for (int reg = 0; reg < 4; reg++) {
          float p = __builtin_amdgcn_exp2f(
              fmaf(S[mi][ni][reg], cs, -ncm[mi][reg]));
          ush hh = f2bf(p);
          ls[mi][reg] += bf2f(hh);   // sum the ROUNDED p: matches PV numerator
          int row = w * 32 + mi * 16 + quad * 4 + reg;
          int cph = ((ni * 2 + (ln15 >> 3)) ^ ((quad * 4 + reg) & 7)) * 8 + (ln15 & 7);
          Ph_[row * 64 + cph] = hh;
        }
#pragma unroll
    for (int mi = 0; mi < 2; mi++)
#pragma unroll
      for (int reg = 0; reg < 4; reg++)
        l_i[mi][reg] += rsum16(ls[mi][reg]);
    __syncthreads();                 // V landed; all waves done reading K
    // ---- phase B: issue K(kt+1) loads; O += P @ V ----
    if (kt + 1 < S_LEN / 64) {
#pragma unroll
      for (int p = 0; p < 2; p++) {
        int r = p * 32 + srow;
        gload16(kh + hoff + (size_t)((kt + 1) * 64 + r) * DK_DIM + gch,
                Kh_ + r * 64 + schunk * 8);
        gload16(kl + hoff + (size_t)((kt + 1) * 64 + r) * DK_DIM + gch,
                Kl_ + r * 64 + schunk * 8);
      }
    }
#pragma unroll
    for (int kc = 0; kc < 2; kc++) {
      int ch = ((kc * 4 + quad) ^ sw) * 8;
      bf16x8 ap[2], bvh[4], bvl[4];
#pragma unroll
      for (int mi = 0; mi < 2; mi++) {
        int row = w * 32 + mi * 16 + ln15;
        ap[mi] = *(const bf16x8*)(Ph_ + row * 64 + ch);
      }
#pragma unroll
      for (int ni = 0; ni < 4; ni++) {
        int row = ni * 16 + ln15;
        bvh[ni] = *(const bf16x8*)(Vh_ + row * 64 + ch);
        bvl[ni] = *(const bf16x8*)(Vl_ + row * 64 + ch);
      }
      __builtin_amdgcn_s_setprio(1);
#pragma unroll
      for (int mi = 0; mi < 2; mi++)
#pragma unroll
        for (int ni = 0; ni < 4; ni++) {
          Oacc[mi][ni] = MFMA(ap[mi], bvh[ni], Oacc[mi][ni]);
          Oacc[mi][ni] = MFMA(ap[mi], bvl[ni], Oacc[mi][ni]);
        }
      __builtin_amdgcn_s_setprio(0);
    }
    __syncthreads();                 // K(kt+1) landed; all waves done with V/P
  }
  // ---- epilogue ----
  float inv[2][4];
#pragma unroll
  for (int mi = 0; mi < 2; mi++)
#pragma unroll
    for (int reg = 0; reg < 4; reg++) inv[mi][reg] = 1.0f / l_i[mi][reg];
  int b = bh >> 4, h = bh & 15;
#pragma unroll
  for (int mi = 0; mi < 2; mi++)
#pragma unroll
    for (int ni = 0; ni < 4; ni++)
#pragma unroll
      for (int reg = 0; reg < 4; reg++) {
        float ov = Oacc[mi][ni][reg] * inv[mi][reg];
        int s = q0 + w * 32 + mi * 16 + quad * 4 + reg;
        int col = h * DK_DIM + ni * 16 + ln15;
        size_t idx = (size_t)(s * B_SZ + b) * D_DIM + col;
        ush hh, ll;
        split2(ov, hh, ll);
        oh[idx] = hh;
        ol[idx] = ll;
      }
}

// ---------------- Wo: out = x + o @ wo + bo (fp32 out) ----------------
__global__ __launch_bounds__(256) void wo_mfma(const ush* __restrict__ oh,
    const ush* __restrict__ ol, const ush* __restrict__ woTh,
    const float* __restrict__ bo, const float* __restrict__ x,
    float* __restrict__ out) {
  __shared__ ush Ash[128][64], Asl[128][64], Bsh[128][64], Bsl[128][64];
  int m0 = blockIdx.x * 128, n0 = blockIdx.y * 128;
  const ush* Bl = woTh + 1048576;
  int tid = threadIdx.x, lane = tid & 63, w = tid >> 6;
  int quad = lane >> 4, ln15 = lane & 15;
  int mb = (w >> 1) * 64, nb = (w & 1) * 64;
  f32x4 acc[4][4] = {};
  split_gemm(oh + (size_t)m0 * D_DIM, ol + (size_t)m0 * D_DIM, D_DIM,
             woTh + (size_t)n0 * D_DIM, Bl + (size_t)n0 * D_DIM, D_DIM, D_DIM,
             tid, acc, Ash, Asl, Bsh, Bsl);
#pragma unroll
  for (int mi = 0; mi < 4; mi++)
#pragma unroll
    for (int reg = 0; reg < 4; reg++) {
      int m = m0 + mb + mi * 16 + quad * 4 + reg;
#pragma unroll
      for (int ni = 0; ni < 4; ni++) {
        int n = n0 + nb + ni * 16 + ln15;
        size_t idx = (size_t)m * D_DIM + n;
        out[idx] = x[idx] + acc[mi][ni][reg] + bo[n];
      }
    }
}

// ------- MoE GEMM1: 2-phase double-buffered + XOR-swizzled LDS -------
__global__ __launch_bounds__(256) void moe1_mfma(const ush* __restrict__ zb,
    const ush* __restrict__ w1t, const float* __restrict__ b1,
    const int* __restrict__ list, const int* __restrict__ offs,
    ush* __restrict__ h) {
  int e = blockIdx.x;
  int n0 = blockIdx.y * 128;
  int mhalf = blockIdx.z;
  int off = offs[e], cnt = offs[e + 1] - off;
  __shared__ ush As[2][128][64], Bs[2][128][64];   // 64 KB
  int tid = threadIdx.x, lane = tid & 63, w = tid >> 6;
  int srw = w * 8 + (lane >> 3);                 // staging row 0..31
  int colb = (lane & 7) * 8;                     // linear LDS dst chunk
  int scol = ((lane & 7) ^ (srw & 7)) * 8;       // swizzled global src chunk
  int mb = (w >> 1) * 64, nb = (w & 1) * 64;
  int quad = lane >> 4, ln15 = lane & 15, sw = ln15 & 7;
  const ush* gB[4];
#pragma unroll
  for (int r = 0; r < 4; r++)
    gB[r] = w1t + ((size_t)e * F_DIM + n0 + r * 32 + srw) * D_DIM + scol;
  const float* be = b1 + (size_t)e * F_DIM;
  for (int m0 = mhalf * 128; m0 < cnt; m0 += 256) {
    const ush* gA[4];
#pragma unroll
    for (int r = 0; r < 4; r++) {
      int ra = m0 + r * 32 + srw; if (ra > cnt - 1) ra = cnt - 1;
      gA[r] = zb + (size_t)list[off + ra] * D_DIM + scol;
    }
#define STG1(buf, kb) do { _Pragma("unroll")                                   \
    for (int r = 0; r < 4; r++) {                                              \
      gload16(gA[r] + (kb), &As[buf][r * 32 + srw][colb]);                     \
      gload16(gB[r] + (kb), &Bs[buf][r * 32 + srw][colb]); } } while (0)
    STG1(0, 0);
    __syncthreads();
    f32x4 acc[4][4] = {};
    for (int ki = 0; ki < 16; ki++) {
      int cur = ki & 1;
      if (ki < 15) STG1(cur ^ 1, (ki + 1) * 64);   // prefetch under compute
#pragma unroll
      for (int kc = 0; kc < 2; kc++) {
        int kof = ((kc * 4 + quad) ^ sw) * 8;
        bf16x8 av[4], bv[4];
#pragma unroll
        for (int i = 0; i < 4; i++) {
          av[i] = *(const bf16x8*)&As[cur][mb + i * 16 + ln15][kof];
          bv[i] = *(const bf16x8*)&Bs[cur][nb + i * 16 + ln15][kof];
        }
#pragma unroll
        for (int mi = 0; mi < 4; mi++)
#pragma unroll
          for (int ni = 0; ni < 4; ni++)
            acc[mi][ni] = MFMA(av[mi], bv[ni], acc[mi][ni]);
      }
      __syncthreads();               // drains prefetch; next buffer ready
    }
#undef STG1
#pragma unroll
    for (int mi = 0; mi < 4; mi++)
#pragma unroll
      for (int reg = 0; reg < 4; reg++) {
        int lm = m0 + mb + mi * 16 + quad * 4 + reg;
        if (lm < cnt) {
#pragma unroll
          for (int ni = 0; ni < 4; ni++) {
            int n = n0 + nb + ni * 16 + ln15;
            float v = acc[mi][ni][reg] + be[n];
            h[(size_t)(off + lm) * F_DIM + n] = f2bf(fmaxf(v, 0.f));
          }
        }
      }
  }
}

// ------- MoE GEMM2: 2-phase double-buffered + XOR-swizzled; split-K=4 -------
__global__ __launch_bounds__(256) void moe2_mfma(const ush* __restrict__ hb,
    const ush* __restrict__ w2t, const float* __restrict__ b2,
    const int* __restrict__ list, const int* __restrict__ offs,
    const float* __restrict__ pmax, float* __restrict__ out) {
  int e = blockIdx.x;
  int n0 = blockIdx.y * 128;
  int ks = blockIdx.z >> 1;
  int mhalf = blockIdx.z & 1;
  int off = offs[e], cnt = offs[e + 1] - off;
  size_t kbase = (size_t)ks * 1024;
  __shared__ ush As[2][128][64], Bs[2][128][64];   // 64 KB
  int tid = threadIdx.x, lane = tid & 63, w = tid >> 6;
  int srw = w * 8 + (lane >> 3);
  int colb = (lane & 7) * 8;
  int scol = ((lane & 7) ^ (srw & 7)) * 8;
  int mb = (w >> 1) * 64, nb = (w & 1) * 64;
  int quad = lane >> 4, ln15 = lane & 15, sw = ln15 & 7;
  const ush* gB[4];
#pragma unroll
  for (int r = 0; r < 4; r++)
    gB[r] = w2t + ((size_t)e * D_DIM + n0 + r * 32 + srw) * F_DIM + kbase + scol;
  const float* be = b2 + (size_t)e * D_DIM;
  for (int m0 = mhalf * 128; m0 < cnt; m0 += 256) {
    const ush* gA[4];
#pragma unroll
    for (int r = 0; r < 4; r++) {
      int ra = m0 + r * 32 + srw; if (ra > cnt - 1) ra = cnt - 1;
      gA[r] = hb + (size_t)(off + ra) * F_DIM + kbase + scol;
    }
#define STG2(buf, kb) do { _Pragma("unroll")                                   \
    for (int r = 0; r < 4; r++) {                                              \
      gload16(gA[r] + (kb), &As[buf][r * 32 + srw][colb]);                     \
      gload16(gB[r] + (kb), &Bs[buf][r * 32 + srw][colb]); } } while (0)
    STG2(0, 0);
    __syncthreads();
    f32x4 acc[4][4] = {};
    for (int ki = 0; ki < 16; ki++) {
      int cur = ki & 1;
      if (ki < 15) STG2(cur ^ 1, (ki + 1) * 64);   // prefetch under compute
#pragma unroll
      for (int kc = 0; kc < 2; kc++) {
        int kof = ((kc * 4 + quad) ^ sw) * 8;
        bf16x8 av[4], bv[4];
#pragma unroll
        for (int i = 0; i < 4; i++) {
          av[i] = *(const bf16x8*)&As[cur][mb + i * 16 + ln15][kof];
          bv[i] = *(const bf16x8*)&Bs[cur][nb + i * 16 + ln15][kof];
        }
#pragma unroll
        for (int mi = 0; mi < 4; mi++)
#pragma unroll
          for (int ni = 0; ni < 4; ni++)
            acc[mi][ni] = MFMA(av[mi], bv[ni], acc[mi][ni]);
      }
      __syncthreads();
    }
#undef STG2
#pragma unroll
    for (int mi = 0; mi < 4; mi++)
#pragma unroll
      for (int reg = 0; reg < 4; reg++) {
        int lm = m0 + mb + mi * 16 + quad * 4 + reg;
        if (lm < cnt) {
          int tok = list[off + lm];
          float p = pmax[tok];
#pragma unroll
          for (int ni = 0; ni < 4; ni++) {
            int n = n0 + nb + ni * 16 + ln15;
            float v = acc[mi][ni][reg];
            if (ks == 0) v += be[n];
            atomicAdd(&out[(size_t)tok * D_DIM + n], v * p);
          }
        }
      }
  }
}

// ------- LN2 + gate fused: NO global atomics; per-token partials -------
__global__ __launch_bounds__(256) void ln2_gate(const float* __restrict__ x,
    const float* __restrict__ g, const float* __restrict__ b,
    const float* __restrict__ wg, const float* __restrict__ bg,
    ush* __restrict__ zb, float* __restrict__ pmax_out, int* __restrict__ route,
    float* __restrict__ rps_partial) {
  int t = blockIdx.x;
  float4 v = ((const float4*)(x + (size_t)t * D_DIM))[threadIdx.x];
  float s = v.x + v.y + v.z + v.w;
  float s2 = v.x * v.x + v.y * v.y + v.z * v.z + v.w * v.w;
#pragma unroll
  for (int off = 32; off > 0; off >>= 1) {
    s += __shfl_down(s, off);
    s2 += __shfl_down(s2, off);
  }
  __shared__ float red[8];
  int wid = threadIdx.x >> 6;
  if ((threadIdx.x & 63) == 0) { red[wid] = s; red[4 + wid] = s2; }
  __syncthreads();
  float sum = red[0] + red[1] + red[2] + red[3];
  float sq = red[4] + red[5] + red[6] + red[7];
  float mu = sum * (1.0f / D_DIM);
  float var = sq * (1.0f / D_DIM) - mu * mu;
  float rstd = rsqrtf(var + 1e-5f);
  float4 gg = ((const float4*)g)[threadIdx.x];
  float4 bb = ((const float4*)b)[threadIdx.x];
  float zz[4];
  zz[0] = (v.x - mu) * rstd * gg.x + bb.x;
  zz[1] = (v.y - mu) * rstd * gg.y + bb.y;
  zz[2] = (v.z - mu) * rstd * gg.z + bb.z;
  zz[3] = (v.w - mu) * rstd * gg.w + bb.w;
  ushort4 u;
  u.x = f2bf(zz[0]); u.y = f2bf(zz[1]); u.z = f2bf(zz[2]); u.w = f2bf(zz[3]);
  *(ushort4*)(zb + (size_t)t * D_DIM + threadIdx.x * 4) = u;
  int d0 = threadIdx.x * 4;
  float acc[8] = {};
  const float* w0 = wg + (size_t)d0 * E_EXP;
#pragma unroll
  for (int i = 0; i < 4; i++)
#pragma unroll
    for (int e = 0; e < 8; e++)
      acc[e] += zz[i] * w0[i * 8 + e];
#pragma unroll
  for (int off = 32; off > 0; off >>= 1)
#pragma unroll
    for (int e = 0; e < 8; e++) acc[e] += __shfl_down(acc[e], off);
  __shared__ float red2[4][8];
  if ((threadIdx.x & 63) == 0)
#pragma unroll
    for (int e = 0; e < 8; e++) red2[threadIdx.x >> 6][e] = acc[e];
  __syncthreads();
  if (threadIdx.x == 0) {
    float lg[8];
#pragma unroll
    for (int e = 0; e < 8; e++)
      lg[e] = red2[0][e] + red2[1][e] + red2[2][e] + red2[3][e] + bg[e];
    float mx = lg[0];
    int am = 0;
#pragma unroll
    for (int e = 1; e < 8; e++)
      if (lg[e] > mx) { mx = lg[e]; am = e; }
    float se = 0.f, pe[8];
#pragma unroll
    for (int e = 0; e < 8; e++) { pe[e] = expf(lg[e] - mx); se += pe[e]; }
    float inv = 1.0f / se;
    pmax_out[t] = inv;
    route[t] = am;
#pragma unroll
    for (int e = 0; e < 8; e++) rps_partial[(size_t)t * 8 + e] = pe[e] * inv;
  }
}

// ------- reduce partials: rps[e] = sum_t partial[t][e]; counts[e] -------
__global__ __launch_bounds__(256) void reduce_gate(const float* __restrict__ rps_partial,
    const int* __restrict__ route, float* __restrict__ rps, int* __restrict__ counts) {
  int e = blockIdx.x;
  float s = 0.f;
  int c = 0;
  for (int t = threadIdx.x; t < T_TOK; t += 256) {
    s += rps_partial[(size_t)t * 8 + e];
    c += (route[t] == e) ? 1 : 0;
  }
#pragma unroll
  for (int off = 32; off > 0; off >>= 1) {
    s += __shfl_down(s, off);
    c += __shfl_down(c, off);
  }
  __shared__ float sred[4];
  __shared__ int cred[4];
  int wid = threadIdx.x >> 6;
  if ((threadIdx.x & 63) == 0) { sred[wid] = s; cred[wid] = c; }
  __syncthreads();
  if (threadIdx.x == 0) {
    rps[e] = sred[0] + sred[1] + sred[2] + sred[3];
    counts[e] = cred[0] + cred[1] + cred[2] + cred[3];
  }
}

__global__ void init_kernel(int* cursor) {
  int i = threadIdx.x;
  if (i < E_EXP) cursor[i] = 0;
}

__global__ void offsets_kernel(const int* counts, int* offs, float* counts_f, float* ndrop) {
  if (threadIdx.x == 0) {
    int o = 0;
    for (int e = 0; e < E_EXP; e++) { offs[e] = o; o += counts[e]; }
    offs[E_EXP] = o;
    for (int e = 0; e < E_EXP; e++) counts_f[e] = (float)counts[e];
    *ndrop = 0.f;
  }
}

// ------- scatter with wave-aggregated atomics (<=512 atomics total) -------
__global__ void scatter_kernel(const int* __restrict__ route, const int* __restrict__ offs,
                               int* __restrict__ cursor, int* __restrict__ list) {
  int t = blockIdx.x * 256 + threadIdx.x;
  int lane = threadIdx.x & 63;
  int e = (t < T_TOK) ? route[t] : -1;
#pragma unroll
  for (int ex = 0; ex < E_EXP; ex++) {
    unsigned long long mask = __ballot(e == ex);
    int cntw = __popcll(mask);
    if (cntw) {
      int leader = __ffsll((unsigned long long)mask) - 1;
      int base = 0;
      if (lane == leader) base = atomicAdd(&cursor[ex], cntw);
      base = __shfl(base, leader);
      if (e == ex) {
        int rank = __popcll(mask & ((1ull << lane) - 1));
        list[offs[ex] + base + rank] = t;
      }
    }
  }
}

extern "C" void kernel_launch(void* const* d_in, const int* in_sizes, int n_in,
                              void* d_out, int out_size, void* d_ws, size_t ws_size,
                              hipStream_t stream) {
  const float* x = (const float*)d_in[0];
  const float* ln1_g = (const float*)d_in[1];
  const float* ln1_b = (const float*)d_in[2];
  const float* ln2_g = (const float*)d_in[3];
  const float* ln2_b = (const float*)d_in[4];
  const float* wq = (const float*)d_in[5];
  const float* bq = (const float*)d_in[6];
  const float* wk = (const float*)d_in[7];
  const float* bk = (const float*)d_in[8];
  const float* wv = (const float*)d_in[9];
  const float* bv = (const float*)d_in[10];
  const float* wo = (const float*)d_in[11];
  const float* bo = (const float*)d_in[12];
  const float* wg = (const float*)d_in[13];
  const float* bg = (const float*)d_in[14];
  const float* w1 = (const float*)d_in[15];
  const float* b1 = (const float*)d_in[16];
  const float* w2 = (const float*)d_in[17];
  const float* b2 = (const float*)d_in[18];

  float* out = (float*)d_out;
  float* counts_f = out + (size_t)T_TOK * D_DIM;
  float* rps = counts_f + E_EXP;
  float* ndrop = rps + E_EXP;
  float* pmax = ndrop + 1;

  const size_t MB1 = 1048576;
  char* base = (char*)d_ws;
  ush* zh  = (ush*)(base + 0 * MB1);
  ush* zl  = (ush*)(base + 8 * MB1);
  ush* qh  = (ush*)(base + 16 * MB1);
  ush* ql  = (ush*)(base + 24 * MB1);
  ush* kh  = (ush*)(base + 32 * MB1);
  ush* kl  = (ush*)(base + 40 * MB1);
  ush* vth = (ush*)(base + 48 * MB1);
  ush* vtl = (ush*)(base + 56 * MB1);
  ush* wT  = (ush*)(base + 64 * MB1);
  ush* oh  = (ush*)(base + 80 * MB1);
  ush* ol  = (ush*)(base + 88 * MB1);
  ush* zb  = (ush*)(base + 64 * MB1);
  ush* hb  = (ush*)(base + 72 * MB1);
  int* route  = (int*)(base + 104 * MB1);
  int* list   = route + T_TOK;
  int* counts = list + T_TOK;
  int* offs   = counts + E_EXP;
  int* cursor = offs + E_EXP + 1;
  float* rps_partial = (float*)(base + 106 * MB1);   // 4096*8*4 = 128 KB
  ush* w1t = (ush*)(base + 0 * MB1);
  ush* w2t = (ush*)(base + 112 * MB1);

  ln1_split<<<T_TOK, 256, 0, stream>>>(x, ln1_g, ln1_b, zh, zl);
  dim3 gt(32, 32);
  transpose_split<<<gt, 256, 0, stream>>>(wq, wT + 0 * 2097152, wT + 0 * 2097152 + 1048576, D_DIM, D_DIM);
  transpose_split<<<gt, 256, 0, stream>>>(wk, wT + 1 * 2097152, wT + 1 * 2097152 + 1048576, D_DIM, D_DIM);
  transpose_split<<<gt, 256, 0, stream>>>(wv, wT + 2 * 2097152, wT + 2 * 2097152 + 1048576, D_DIM, D_DIM);
  transpose_split<<<gt, 256, 0, stream>>>(wo, wT + 3 * 2097152, wT + 3 * 2097152 + 1048576, D_DIM, D_DIM);
  dim3 gq(32, 8, 3);
  qkv_mfma<<<gq, 256, 0, stream>>>(zh, zl, wT, bq, bk, bv, qh, kh, vth);
  dim3 ga(S_LEN / 128, B_SZ * H_HEADS);
  attn_mfma<<<ga, 256, 0, stream>>>(qh, ql, kh, kl, vth, vtl, oh, ol);
  dim3 gt1(F_DIM / 32, D_DIM / 32, E_EXP);
  transpose_bf16<<<gt1, 256, 0, stream>>>(w1, w1t, D_DIM, F_DIM);
  dim3 gt2(D_DIM / 32, F_DIM / 32, E_EXP);
  transpose_bf16<<<gt2, 256, 0, stream>>>(w2, w2t, F_DIM, D_DIM);
  dim3 gw(32, 8);
  wo_mfma<<<gw, 256, 0, stream>>>(oh, ol, wT + 3 * 2097152, bo, x, out);
  init_kernel<<<1, 64, 0, stream>>>(cursor);
  ln2_gate<<<T_TOK, 256, 0, stream>>>(out, ln2_g, ln2_b, wg, bg, zb, pmax, route, rps_partial);
  reduce_gate<<<E_EXP, 256, 0, stream>>>(rps_partial, route, rps, counts);
  offsets_kernel<<<1, 64, 0, stream>>>(counts, offs, counts_f, ndrop);
  scatter_kernel<<<16, 256, 0, stream>>>(route, offs, cursor, list);
  dim3 gm1(E_EXP, F_DIM / 128, 2);
  moe1_mfma<<<gm1, 256, 0, stream>>>(zb, w1t, b1, list, offs, hb);
  dim3 gm2(E_EXP, D_DIM / 128, 8);
  moe2_mfma<<<gm2, 256, 0, stream>>>(hb, w2t, b2, list, offs, pmax, out);
}

// Round 4
// 851.873 us; speedup vs baseline: 1.0405x; 1.0405x over previous
//
#include <hip/hip_runtime.h>

#define S_LEN 2048
#define B_SZ 2
#define D_DIM 1024
#define H_HEADS 16
#define DK_DIM 64
#define E_EXP 8
#define F_DIM 4096
#define T_TOK 4096   // S*B

typedef unsigned short ush;
typedef __bf16 bf16x8 __attribute__((ext_vector_type(8)));
typedef float f32x4 __attribute__((ext_vector_type(4)));

__device__ __forceinline__ ush f2bf(float f) {
  union { __bf16 h; ush u; } cv;
  cv.h = (__bf16)f;
  return cv.u;
}

__device__ __forceinline__ float bf2f(ush u) {
  union { unsigned int i; float f; } cv;
  cv.i = ((unsigned int)u) << 16;
  return cv.f;
}

// split v into hi + lo bf16 (v ~= hi + lo, rel err ~2^-17)
__device__ __forceinline__ void split2(float v, ush& h, ush& l) {
  ush hh = f2bf(v);
  h = hh;
  l = f2bf(v - bf2f(hh));
}

__device__ __forceinline__ void gload16(const void* g, void* l) {
  __builtin_amdgcn_global_load_lds(
      (const __attribute__((address_space(1))) unsigned int*)g,
      (__attribute__((address_space(3))) unsigned int*)l, 16, 0, 0);
}

#define MFMA(a, b, c) __builtin_amdgcn_mfma_f32_16x16x32_bf16(a, b, c, 0, 0, 0)

// ---- DPP 16-lane all-reduce (pure VALU, replaces ds_bpermute shuffles) ----
template <int CTRL>
__device__ __forceinline__ float dpp_mov(float x) {
  return __builtin_bit_cast(float,
      __builtin_amdgcn_update_dpp(0, __builtin_bit_cast(int, x), CTRL, 0xF, 0xF,
                                  true));
}
__device__ __forceinline__ float rmax16(float x) {
  x = fmaxf(x, dpp_mov<0xB1>(x));    // quad_perm xor1
  x = fmaxf(x, dpp_mov<0x4E>(x));    // quad_perm xor2
  x = fmaxf(x, dpp_mov<0x141>(x));   // row_half_mirror
  x = fmaxf(x, dpp_mov<0x140>(x));   // row_mirror
  return x;
}
__device__ __forceinline__ float rsum16(float x) {
  x += dpp_mov<0xB1>(x);
  x += dpp_mov<0x4E>(x);
  x += dpp_mov<0x141>(x);
  x += dpp_mov<0x140>(x);
  return x;
}

// ---------------- LN1: x -> split bf16 z ----------------
__global__ __launch_bounds__(256) void ln1_split(const float* __restrict__ x,
    const float* __restrict__ g, const float* __restrict__ b,
    ush* __restrict__ zh, ush* __restrict__ zl) {
  int t = blockIdx.x;
  float4 v = ((const float4*)(x + (size_t)t * D_DIM))[threadIdx.x];
  float s = v.x + v.y + v.z + v.w;
  float s2 = v.x * v.x + v.y * v.y + v.z * v.z + v.w * v.w;
#pragma unroll
  for (int off = 32; off > 0; off >>= 1) {
    s += __shfl_down(s, off);
    s2 += __shfl_down(s2, off);
  }
  __shared__ float red[8];
  int wid = threadIdx.x >> 6;
  if ((threadIdx.x & 63) == 0) { red[wid] = s; red[4 + wid] = s2; }
  __syncthreads();
  float sum = red[0] + red[1] + red[2] + red[3];
  float sq = red[4] + red[5] + red[6] + red[7];
  float mu = sum * (1.0f / D_DIM);
  float var = sq * (1.0f / D_DIM) - mu * mu;
  float rstd = rsqrtf(var + 1e-5f);
  float4 gg = ((const float4*)g)[threadIdx.x];
  float4 bb = ((const float4*)b)[threadIdx.x];
  float o[4];
  o[0] = (v.x - mu) * rstd * gg.x + bb.x;
  o[1] = (v.y - mu) * rstd * gg.y + bb.y;
  o[2] = (v.z - mu) * rstd * gg.z + bb.z;
  o[3] = (v.w - mu) * rstd * gg.w + bb.w;
  ushort4 uh, ul;
  split2(o[0], uh.x, ul.x); split2(o[1], uh.y, ul.y);
  split2(o[2], uh.z, ul.z); split2(o[3], uh.w, ul.w);
  *(ushort4*)(zh + (size_t)t * D_DIM + threadIdx.x * 4) = uh;
  *(ushort4*)(zl + (size_t)t * D_DIM + threadIdx.x * 4) = ul;
}

// ------------- transpose fp32 [R][C] -> split bf16 [C][R] -------------
__global__ __launch_bounds__(256) void transpose_split(const float* __restrict__ in,
    ush* __restrict__ outh, ush* __restrict__ outl, int R, int C) {
  __shared__ float tile[32][33];
  int c0 = blockIdx.x * 32, r0 = blockIdx.y * 32;
  int tx = threadIdx.x & 31, ty = threadIdx.x >> 5;
#pragma unroll
  for (int i = 0; i < 4; i++)
    tile[ty + i * 8][tx] = in[(size_t)(r0 + ty + i * 8) * C + c0 + tx];
  __syncthreads();
#pragma unroll
  for (int i = 0; i < 4; i++) {
    float v = tile[tx][ty + i * 8];
    ush h, l;
    split2(v, h, l);
    size_t idx = (size_t)(c0 + ty + i * 8) * R + r0 + tx;
    outh[idx] = h;
    outl[idx] = l;
  }
}

// ------------- transpose fp32 [E][R][C] -> plain bf16 [E][C][R] -------------
__global__ __launch_bounds__(256) void transpose_bf16(const float* __restrict__ in,
    ush* __restrict__ out, int R, int C) {
  __shared__ float tile[32][33];
  int e = blockIdx.z;
  const float* ip = in + (size_t)e * R * C;
  ush* op = out + (size_t)e * R * C;
  int c0 = blockIdx.x * 32, r0 = blockIdx.y * 32;
  int tx = threadIdx.x & 31, ty = threadIdx.x >> 5;
#pragma unroll
  for (int i = 0; i < 4; i++)
    tile[ty + i * 8][tx] = ip[(size_t)(r0 + ty + i * 8) * C + c0 + tx];
  __syncthreads();
#pragma unroll
  for (int i = 0; i < 4; i++)
    op[(size_t)(c0 + ty + i * 8) * R + r0 + tx] = f2bf(tile[tx][ty + i * 8]);
}

// ------- split-bf16 GEMM core: 128x128 tile, BK=64, XOR-swizzled LDS -------
__device__ __forceinline__ void split_gemm(const ush* __restrict__ Ah,
    const ush* __restrict__ Al, int lda, const ush* __restrict__ Bh,
    const ush* __restrict__ Bl, int ldb, int K, int tid, f32x4 acc[4][4],
    ush (*Ash)[64], ush (*Asl)[64], ush (*Bsh)[64], ush (*Bsl)[64]) {
  int lane = tid & 63, w = tid >> 6, quad = lane >> 4, ln15 = lane & 15;
  int srow = tid >> 3, pcol = (tid & 7) * 8;
  int scol = ((tid & 7) ^ (srow & 7)) * 8;   // swizzled global source chunk
  int sw = ln15 & 7;                         // frag-read swizzle key
  int mb = (w >> 1) * 64, nb = (w & 1) * 64;
  for (int kb = 0; kb < K; kb += 64) {
    __syncthreads();
#pragma unroll
    for (int r = 0; r < 4; r++) {
      int rr = r * 32 + srow;
      gload16(Ah + (size_t)rr * lda + kb + scol, &Ash[rr][pcol]);
      gload16(Al + (size_t)rr * lda + kb + scol, &Asl[rr][pcol]);
      gload16(Bh + (size_t)rr * ldb + kb + scol, &Bsh[rr][pcol]);
      gload16(Bl + (size_t)rr * ldb + kb + scol, &Bsl[rr][pcol]);
    }
    __syncthreads();
#pragma unroll
    for (int kc = 0; kc < 2; kc++) {
      int kof = ((kc * 4 + quad) ^ sw) * 8;
      bf16x8 avh[4], avl[4], bvh[4], bvl[4];
#pragma unroll
      for (int i = 0; i < 4; i++) {
        avh[i] = *(const bf16x8*)&Ash[mb + i * 16 + ln15][kof];
        avl[i] = *(const bf16x8*)&Asl[mb + i * 16 + ln15][kof];
        bvh[i] = *(const bf16x8*)&Bsh[nb + i * 16 + ln15][kof];
        bvl[i] = *(const bf16x8*)&Bsl[nb + i * 16 + ln15][kof];
      }
#pragma unroll
      for (int mi = 0; mi < 4; mi++)
#pragma unroll
        for (int ni = 0; ni < 4; ni++) {
          acc[mi][ni] = MFMA(avh[mi], bvh[ni], acc[mi][ni]);
          acc[mi][ni] = MFMA(avh[mi], bvl[ni], acc[mi][ni]);
          acc[mi][ni] = MFMA(avl[mi], bvh[ni], acc[mi][ni]);
        }
    }
  }
}

// ---------------- QKV: z @ w{q,k,v} + bias -> split bf16 ----------------
__global__ __launch_bounds__(256) void qkv_mfma(const ush* __restrict__ zh,
    const ush* __restrict__ zl, const ush* __restrict__ wT,
    const float* __restrict__ bq, const float* __restrict__ bk,
    const float* __restrict__ bv, ush* __restrict__ qh_, ush* __restrict__ kh_,
    ush* __restrict__ vth_) {
  __shared__ ush Ash[128][64], Asl[128][64], Bsh[128][64], Bsl[128][64];
  int z = blockIdx.z;
  int m0 = blockIdx.x * 128, n0 = blockIdx.y * 128;
  const ush* Bh = wT + (size_t)z * 2097152;
  const ush* Bl = Bh + 1048576;
  const float* bias = (z == 0) ? bq : (z == 1) ? bk : bv;
  ush* outh = (z == 0) ? qh_ : (z == 1) ? kh_ : vth_;
  int tid = threadIdx.x, lane = tid & 63, w = tid >> 6;
  int quad = lane >> 4, ln15 = lane & 15;
  int mb = (w >> 1) * 64, nb = (w & 1) * 64;
  f32x4 acc[4][4] = {};
  split_gemm(zh + (size_t)m0 * D_DIM, zl + (size_t)m0 * D_DIM, D_DIM,
             Bh + (size_t)n0 * D_DIM, Bl + (size_t)n0 * D_DIM, D_DIM, D_DIM,
             tid, acc, Ash, Asl, Bsh, Bsl);
#pragma unroll
  for (int mi = 0; mi < 4; mi++)
#pragma unroll
    for (int reg = 0; reg < 4; reg++) {
      int m = m0 + mb + mi * 16 + quad * 4 + reg;
      int s = m >> 1, b = m & 1;
#pragma unroll
      for (int ni = 0; ni < 4; ni++) {
        int n = n0 + nb + ni * 16 + ln15;
        float val = acc[mi][ni][reg] + bias[n];
        ush hh, ll;
        split2(val, hh, ll);
        int h = n >> 6, dk = n & 63;
        size_t idx;
        if (z < 2) idx = ((size_t)(b * H_HEADS + h) * S_LEN + s) * DK_DIM + dk;
        else       idx = ((size_t)(b * H_HEADS + h) * DK_DIM + dk) * S_LEN + s;
        outh[idx] = hh;
        outh[idx + 4194304] = ll;   // lo buffer is +8 MB after hi
      }
    }
}

// ---------------- Flash attention v3 (unchanged) ----------------
__global__ __launch_bounds__(256, 2) void attn_mfma(const ush* __restrict__ qh,
    const ush* __restrict__ ql, const ush* __restrict__ kh,
    const ush* __restrict__ kl, const ush* __restrict__ vth,
    const ush* __restrict__ vtl, ush* __restrict__ oh, ush* __restrict__ ol) {
  int bh = blockIdx.y, q0 = blockIdx.x * 128;
  const size_t hoff = (size_t)bh * S_LEN * DK_DIM;
  __shared__ float4 smemv[3072];       // 48 KB
  ush* Ph_ = (ush*)smemv;              // [128][64] bf16 P (wave-private rows)
  ush* Kh_ = (ush*)smemv + 8192;       // [64][64]
  ush* Kl_ = (ush*)smemv + 12288;
  ush* Vh_ = (ush*)smemv + 16384;      // [64][64] (Vt: row=dk, col=key)
  ush* Vl_ = (ush*)smemv + 20480;
  int tid = threadIdx.x, lane = tid & 63, w = tid >> 6;
  int quad = lane >> 4, ln15 = lane & 15;
  int srow = tid >> 3;                 // staging row 0..31
  int schunk = tid & 7;                // LDS dst chunk (fixed by gload16)
  int gch = (schunk ^ (srow & 7)) * 8; // swizzled global source chunk (ush)
  int sw = ln15 & 7;                   // frag-read swizzle key
  // ---- prologue: issue K-tile 0 loads; Q fragments direct from global ----
#pragma unroll
  for (int p = 0; p < 2; p++) {
    int r = p * 32 + srow;
    gload16(kh + hoff + (size_t)r * DK_DIM + gch, Kh_ + r * 64 + schunk * 8);
    gload16(kl + hoff + (size_t)r * DK_DIM + gch, Kl_ + r * 64 + schunk * 8);
  }
  bf16x8 Qf[2][2][2];   // [mi][kc][hi/lo]
#pragma unroll
  for (int mi = 0; mi < 2; mi++)
#pragma unroll
    for (int kc = 0; kc < 2; kc++) {
      size_t qidx = hoff + (size_t)(q0 + w * 32 + mi * 16 + ln15) * DK_DIM +
                    (kc * 4 + quad) * 8;
      Qf[mi][kc][0] = *(const bf16x8*)(qh + qidx);
      Qf[mi][kc][1] = *(const bf16x8*)(ql + qidx);
    }
  f32x4 Oacc[2][4] = {};
  float m_i[2][4], l_i[2][4];
#pragma unroll
  for (int mi = 0; mi < 2; mi++)
#pragma unroll
    for (int r = 0; r < 4; r++) { m_i[mi][r] = -3e38f; l_i[mi][r] = 0.f; }
  const float cs = 0.18033688f;        // 0.125 * log2(e): exp2-domain softmax
  __syncthreads();                     // K0 landed
  for (int kt = 0; kt < S_LEN / 64; kt++) {
    // ---- phase A: issue V(kt) loads; QK^T; softmax; store P ----
#pragma unroll
    for (int p = 0; p < 2; p++) {
      int r = p * 32 + srow;
      gload16(vth + hoff + (size_t)r * S_LEN + kt * 64 + gch,
              Vh_ + r * 64 + schunk * 8);
      gload16(vtl + hoff + (size_t)r * S_LEN + kt * 64 + gch,
              Vl_ + r * 64 + schunk * 8);
    }
    f32x4 S[2][4] = {};
#pragma unroll
    for (int kc = 0; kc < 2; kc++) {
      int ch = ((kc * 4 + quad) ^ sw) * 8;
      bf16x8 bkh[4], bkl[4];
#pragma unroll
      for (int ni = 0; ni < 4; ni++) {
        int row = ni * 16 + ln15;
        bkh[ni] = *(const bf16x8*)(Kh_ + row * 64 + ch);
        bkl[ni] = *(const bf16x8*)(Kl_ + row * 64 + ch);
      }
      __builtin_amdgcn_s_setprio(1);
#pragma unroll
      for (int mi = 0; mi < 2; mi++)
#pragma unroll
        for (int ni = 0; ni < 4; ni++) {
          S[mi][ni] = MFMA(Qf[mi][kc][0], bkh[ni], S[mi][ni]);
          S[mi][ni] = MFMA(Qf[mi][kc][0], bkl[ni], S[mi][ni]);
          S[mi][ni] = MFMA(Qf[mi][kc][1], bkh[ni], S[mi][ni]);
        }
      __builtin_amdgcn_s_setprio(0);
    }
    // ---- online softmax: row max via DPP (raw units) ----
    float mt[2][4];
#pragma unroll
    for (int mi = 0; mi < 2; mi++)
#pragma unroll
      for (int reg = 0; reg < 4; reg++) {
        float m = fmaxf(fmaxf(S[mi][0][reg], S[mi][1][reg]),
                        fmaxf(S[mi][2][reg], S[mi][3][reg]));
        mt[mi][reg] = rmax16(m);
      }
    // ---- deferred-max rescale (T13) ----
    float growth = -3e38f;
#pragma unroll
    for (int mi = 0; mi < 2; mi++)
#pragma unroll
      for (int reg = 0; reg < 4; reg++)
        growth = fmaxf(growth, mt[mi][reg] - m_i[mi][reg]);
    if (__any(growth > 44.3614195f)) {   // 8 / cs  =>  p bounded by 2^8
#pragma unroll
      for (int mi = 0; mi < 2; mi++)
#pragma unroll
        for (int reg = 0; reg < 4; reg++) {
          float mnew = fmaxf(m_i[mi][reg], mt[mi][reg]);
          float a = __builtin_amdgcn_exp2f(cs * (m_i[mi][reg] - mnew));
          m_i[mi][reg] = mnew;
          l_i[mi][reg] *= a;
#pragma unroll
          for (int ni = 0; ni < 4; ni++) Oacc[mi][ni][reg] *= a;
        }
    }
    float ncm[2][4], ls[2][4] = {};
#pragma unroll
    for (int mi = 0; mi < 2; mi++)
#pragma unroll
      for (int reg = 0; reg < 4; reg++) ncm[mi][reg] = cs * m_i[mi][reg];
#pragma unroll
    for (int mi = 0; mi < 2; mi++)
#pragma unroll
      for (int ni = 0; ni < 4; ni++)
#pragma unroll
        for (int reg = 0; reg < 4; reg++) {
          float p = __builtin_amdgcn_exp2f(
              fmaf(S[mi][ni][reg], cs, -ncm[mi][reg]));
          ush hh = f2bf(p);
          ls[mi][reg] += bf2f(hh);   // sum the ROUNDED p: matches PV numerator
          int row = w * 32 + mi * 16 + quad * 4 + reg;
          int cph = ((ni * 2 + (ln15 >> 3)) ^ ((quad * 4 + reg) & 7)) * 8 + (ln15 & 7);
          Ph_[row * 64 + cph] = hh;
        }
#pragma unroll
    for (int mi = 0; mi < 2; mi++)
#pragma unroll
      for (int reg = 0; reg < 4; reg++)
        l_i[mi][reg] += rsum16(ls[mi][reg]);
    __syncthreads();                 // V landed; all waves done reading K
    // ---- phase B: issue K(kt+1) loads; O += P @ V ----
    if (kt + 1 < S_LEN / 64) {
#pragma unroll
      for (int p = 0; p < 2; p++) {
        int r = p * 32 + srow;
        gload16(kh + hoff + (size_t)((kt + 1) * 64 + r) * DK_DIM + gch,
                Kh_ + r * 64 + schunk * 8);
        gload16(kl + hoff + (size_t)((kt + 1) * 64 + r) * DK_DIM + gch,
                Kl_ + r * 64 + schunk * 8);
      }
    }
#pragma unroll
    for (int kc = 0; kc < 2; kc++) {
      int ch = ((kc * 4 + quad) ^ sw) * 8;
      bf16x8 ap[2], bvh[4], bvl[4];
#pragma unroll
      for (int mi = 0; mi < 2; mi++) {
        int row = w * 32 + mi * 16 + ln15;
        ap[mi] = *(const bf16x8*)(Ph_ + row * 64 + ch);
      }
#pragma unroll
      for (int ni = 0; ni < 4; ni++) {
        int row = ni * 16 + ln15;
        bvh[ni] = *(const bf16x8*)(Vh_ + row * 64 + ch);
        bvl[ni] = *(const bf16x8*)(Vl_ + row * 64 + ch);
      }
      __builtin_amdgcn_s_setprio(1);
#pragma unroll
      for (int mi = 0; mi < 2; mi++)
#pragma unroll
        for (int ni = 0; ni < 4; ni++) {
          Oacc[mi][ni] = MFMA(ap[mi], bvh[ni], Oacc[mi][ni]);
          Oacc[mi][ni] = MFMA(ap[mi], bvl[ni], Oacc[mi][ni]);
        }
      __builtin_amdgcn_s_setprio(0);
    }
    __syncthreads();                 // K(kt+1) landed; all waves done with V/P
  }
  // ---- epilogue ----
  float inv[2][4];
#pragma unroll
  for (int mi = 0; mi < 2; mi++)
#pragma unroll
    for (int reg = 0; reg < 4; reg++) inv[mi][reg] = 1.0f / l_i[mi][reg];
  int b = bh >> 4, h = bh & 15;
#pragma unroll
  for (int mi = 0; mi < 2; mi++)
#pragma unroll
    for (int ni = 0; ni < 4; ni++)
#pragma unroll
      for (int reg = 0; reg < 4; reg++) {
        float ov = Oacc[mi][ni][reg] * inv[mi][reg];
        int s = q0 + w * 32 + mi * 16 + quad * 4 + reg;
        int col = h * DK_DIM + ni * 16 + ln15;
        size_t idx = (size_t)(s * B_SZ + b) * D_DIM + col;
        ush hh, ll;
        split2(ov, hh, ll);
        oh[idx] = hh;
        ol[idx] = ll;
      }
}

// ---------------- Wo: out = x + o @ wo + bo (fp32 out) ----------------
__global__ __launch_bounds__(256) void wo_mfma(const ush* __restrict__ oh,
    const ush* __restrict__ ol, const ush* __restrict__ woTh,
    const float* __restrict__ bo, const float* __restrict__ x,
    float* __restrict__ out) {
  __shared__ ush Ash[128][64], Asl[128][64], Bsh[128][64], Bsl[128][64];
  int m0 = blockIdx.x * 128, n0 = blockIdx.y * 128;
  const ush* Bl = woTh + 1048576;
  int tid = threadIdx.x, lane = tid & 63, w = tid >> 6;
  int quad = lane >> 4, ln15 = lane & 15;
  int mb = (w >> 1) * 64, nb = (w & 1) * 64;
  f32x4 acc[4][4] = {};
  split_gemm(oh + (size_t)m0 * D_DIM, ol + (size_t)m0 * D_DIM, D_DIM,
             woTh + (size_t)n0 * D_DIM, Bl + (size_t)n0 * D_DIM, D_DIM, D_DIM,
             tid, acc, Ash, Asl, Bsh, Bsl);
#pragma unroll
  for (int mi = 0; mi < 4; mi++)
#pragma unroll
    for (int reg = 0; reg < 4; reg++) {
      int m = m0 + mb + mi * 16 + quad * 4 + reg;
#pragma unroll
      for (int ni = 0; ni < 4; ni++) {
        int n = n0 + nb + ni * 16 + ln15;
        size_t idx = (size_t)m * D_DIM + n;
        out[idx] = x[idx] + acc[mi][ni][reg] + bo[n];
      }
    }
}

// ------- MoE GEMM1: single-buffer 32KB (4 blk/CU) + swizzle + XCD e-locality -
// 1D grid 512: e = id&7 (same expert -> same XCD L2), mhalf = (id>>3)&1,
// n0-tile = (id>>4)&31. zb expert slice (~1MB) becomes XCD-L2 resident.
__global__ __launch_bounds__(256) void moe1_mfma(const ush* __restrict__ zb,
    const ush* __restrict__ w1t, const float* __restrict__ b1,
    const int* __restrict__ list, const int* __restrict__ offs,
    ush* __restrict__ h) {
  int id = blockIdx.x;
  int e = id & 7;
  int mhalf = (id >> 3) & 1;
  int n0 = ((id >> 4) & 31) * 128;
  int off = offs[e], cnt = offs[e + 1] - off;
  __shared__ ush As[128][64], Bs[128][64];   // 32 KB
  int tid = threadIdx.x, lane = tid & 63, w = tid >> 6;
  int srw = w * 8 + (lane >> 3);                 // staging row 0..31
  int colb = (lane & 7) * 8;                     // linear LDS dst chunk
  int scol = ((lane & 7) ^ (srw & 7)) * 8;       // swizzled global src chunk
  int mb = (w >> 1) * 64, nb = (w & 1) * 64;
  int quad = lane >> 4, ln15 = lane & 15, sw = ln15 & 7;
  const ush* gB[4];
#pragma unroll
  for (int r = 0; r < 4; r++)
    gB[r] = w1t + ((size_t)e * F_DIM + n0 + r * 32 + srw) * D_DIM + scol;
  const float* be = b1 + (size_t)e * F_DIM;
  for (int m0 = mhalf * 128; m0 < cnt; m0 += 256) {
    const ush* gA[4];
#pragma unroll
    for (int r = 0; r < 4; r++) {
      int ra = m0 + r * 32 + srw; if (ra > cnt - 1) ra = cnt - 1;
      gA[r] = zb + (size_t)list[off + ra] * D_DIM + scol;
    }
    f32x4 acc[4][4] = {};
    for (int kb = 0; kb < D_DIM; kb += 64) {
      __syncthreads();
#pragma unroll
      for (int r = 0; r < 4; r++) {
        gload16(gA[r] + kb, &As[r * 32 + srw][colb]);
        gload16(gB[r] + kb, &Bs[r * 32 + srw][colb]);
      }
      __syncthreads();
#pragma unroll
      for (int kc = 0; kc < 2; kc++) {
        int kof = ((kc * 4 + quad) ^ sw) * 8;
        bf16x8 av[4], bv[4];
#pragma unroll
        for (int i = 0; i < 4; i++) {
          av[i] = *(const bf16x8*)&As[mb + i * 16 + ln15][kof];
          bv[i] = *(const bf16x8*)&Bs[nb + i * 16 + ln15][kof];
        }
#pragma unroll
        for (int mi = 0; mi < 4; mi++)
#pragma unroll
          for (int ni = 0; ni < 4; ni++)
            acc[mi][ni] = MFMA(av[mi], bv[ni], acc[mi][ni]);
      }
    }
#pragma unroll
    for (int mi = 0; mi < 4; mi++)
#pragma unroll
      for (int reg = 0; reg < 4; reg++) {
        int lm = m0 + mb + mi * 16 + quad * 4 + reg;
        if (lm < cnt) {
#pragma unroll
          for (int ni = 0; ni < 4; ni++) {
            int n = n0 + nb + ni * 16 + ln15;
            float v = acc[mi][ni][reg] + be[n];
            h[(size_t)(off + lm) * F_DIM + n] = f2bf(fmaxf(v, 0.f));
          }
        }
      }
  }
}

// ------- MoE GEMM2: single-buffer 32KB + swizzle + XCD e-locality; splitK=4 --
// 1D grid 512: e = id&7, mhalf = (id>>3)&1, n0 = (id>>4)&7, ks = (id>>7)&3.
// hb ks-slice per expert (~1MB) becomes XCD-L2 resident across its 16 blocks.
__global__ __launch_bounds__(256) void moe2_mfma(const ush* __restrict__ hb,
    const ush* __restrict__ w2t, const float* __restrict__ b2,
    const int* __restrict__ list, const int* __restrict__ offs,
    const float* __restrict__ pmax, float* __restrict__ out) {
  int id = blockIdx.x;
  int e = id & 7;
  int mhalf = (id >> 3) & 1;
  int n0 = ((id >> 4) & 7) * 128;
  int ks = (id >> 7) & 3;
  int off = offs[e], cnt = offs[e + 1] - off;
  size_t kbase = (size_t)ks * 1024;
  __shared__ ush As[128][64], Bs[128][64];   // 32 KB
  int tid = threadIdx.x, lane = tid & 63, w = tid >> 6;
  int srw = w * 8 + (lane >> 3);
  int colb = (lane & 7) * 8;
  int scol = ((lane & 7) ^ (srw & 7)) * 8;
  int mb = (w >> 1) * 64, nb = (w & 1) * 64;
  int quad = lane >> 4, ln15 = lane & 15, sw = ln15 & 7;
  const ush* gB[4];
#pragma unroll
  for (int r = 0; r < 4; r++)
    gB[r] = w2t + ((size_t)e * D_DIM + n0 + r * 32 + srw) * F_DIM + kbase + scol;
  const float* be = b2 + (size_t)e * D_DIM;
  for (int m0 = mhalf * 128; m0 < cnt; m0 += 256) {
    const ush* gA[4];
#pragma unroll
    for (int r = 0; r < 4; r++) {
      int ra = m0 + r * 32 + srw; if (ra > cnt - 1) ra = cnt - 1;
      gA[r] = hb + (size_t)(off + ra) * F_DIM + kbase + scol;
    }
    f32x4 acc[4][4] = {};
    for (int kb = 0; kb < 1024; kb += 64) {
      __syncthreads();
#pragma unroll
      for (int r = 0; r < 4; r++) {
        gload16(gA[r] + kb, &As[r * 32 + srw][colb]);
        gload16(gB[r] + kb, &Bs[r * 32 + srw][colb]);
      }
      __syncthreads();
#pragma unroll
      for (int kc = 0; kc < 2; kc++) {
        int kof = ((kc * 4 + quad) ^ sw) * 8;
        bf16x8 av[4], bv[4];
#pragma unroll
        for (int i = 0; i < 4; i++) {
          av[i] = *(const bf16x8*)&As[mb + i * 16 + ln15][kof];
          bv[i] = *(const bf16x8*)&Bs[nb + i * 16 + ln15][kof];
        }
#pragma unroll
        for (int mi = 0; mi < 4; mi++)
#pragma unroll
          for (int ni = 0; ni < 4; ni++)
            acc[mi][ni] = MFMA(av[mi], bv[ni], acc[mi][ni]);
      }
    }
#pragma unroll
    for (int mi = 0; mi < 4; mi++)
#pragma unroll
      for (int reg = 0; reg < 4; reg++) {
        int lm = m0 + mb + mi * 16 + quad * 4 + reg;
        if (lm < cnt) {
          int tok = list[off + lm];
          float p = pmax[tok];
#pragma unroll
          for (int ni = 0; ni < 4; ni++) {
            int n = n0 + nb + ni * 16 + ln15;
            float v = acc[mi][ni][reg];
            if (ks == 0) v += be[n];
            atomicAdd(&out[(size_t)tok * D_DIM + n], v * p);
          }
        }
      }
  }
}

// ------- LN2 + gate fused: NO global atomics; per-token partials -------
__global__ __launch_bounds__(256) void ln2_gate(const float* __restrict__ x,
    const float* __restrict__ g, const float* __restrict__ b,
    const float* __restrict__ wg, const float* __restrict__ bg,
    ush* __restrict__ zb, float* __restrict__ pmax_out, int* __restrict__ route,
    float* __restrict__ rps_partial) {
  int t = blockIdx.x;
  float4 v = ((const float4*)(x + (size_t)t * D_DIM))[threadIdx.x];
  float s = v.x + v.y + v.z + v.w;
  float s2 = v.x * v.x + v.y * v.y + v.z * v.z + v.w * v.w;
#pragma unroll
  for (int off = 32; off > 0; off >>= 1) {
    s += __shfl_down(s, off);
    s2 += __shfl_down(s2, off);
  }
  __shared__ float red[8];
  int wid = threadIdx.x >> 6;
  if ((threadIdx.x & 63) == 0) { red[wid] = s; red[4 + wid] = s2; }
  __syncthreads();
  float sum = red[0] + red[1] + red[2] + red[3];
  float sq = red[4] + red[5] + red[6] + red[7];
  float mu = sum * (1.0f / D_DIM);
  float var = sq * (1.0f / D_DIM) - mu * mu;
  float rstd = rsqrtf(var + 1e-5f);
  float4 gg = ((const float4*)g)[threadIdx.x];
  float4 bb = ((const float4*)b)[threadIdx.x];
  float zz[4];
  zz[0] = (v.x - mu) * rstd * gg.x + bb.x;
  zz[1] = (v.y - mu) * rstd * gg.y + bb.y;
  zz[2] = (v.z - mu) * rstd * gg.z + bb.z;
  zz[3] = (v.w - mu) * rstd * gg.w + bb.w;
  ushort4 u;
  u.x = f2bf(zz[0]); u.y = f2bf(zz[1]); u.z = f2bf(zz[2]); u.w = f2bf(zz[3]);
  *(ushort4*)(zb + (size_t)t * D_DIM + threadIdx.x * 4) = u;
  int d0 = threadIdx.x * 4;
  float acc[8] = {};
  const float* w0 = wg + (size_t)d0 * E_EXP;
#pragma unroll
  for (int i = 0; i < 4; i++)
#pragma unroll
    for (int e = 0; e < 8; e++)
      acc[e] += zz[i] * w0[i * 8 + e];
#pragma unroll
  for (int off = 32; off > 0; off >>= 1)
#pragma unroll
    for (int e = 0; e < 8; e++) acc[e] += __shfl_down(acc[e], off);
  __shared__ float red2[4][8];
  if ((threadIdx.x & 63) == 0)
#pragma unroll
    for (int e = 0; e < 8; e++) red2[threadIdx.x >> 6][e] = acc[e];
  __syncthreads();
  if (threadIdx.x == 0) {
    float lg[8];
#pragma unroll
    for (int e = 0; e < 8; e++)
      lg[e] = red2[0][e] + red2[1][e] + red2[2][e] + red2[3][e] + bg[e];
    float mx = lg[0];
    int am = 0;
#pragma unroll
    for (int e = 1; e < 8; e++)
      if (lg[e] > mx) { mx = lg[e]; am = e; }
    float se = 0.f, pe[8];
#pragma unroll
    for (int e = 0; e < 8; e++) { pe[e] = expf(lg[e] - mx); se += pe[e]; }
    float inv = 1.0f / se;
    pmax_out[t] = inv;
    route[t] = am;
#pragma unroll
    for (int e = 0; e < 8; e++) rps_partial[(size_t)t * 8 + e] = pe[e] * inv;
  }
}

// ------- reduce partials: rps[e] = sum_t partial[t][e]; counts[e] -------
__global__ __launch_bounds__(256) void reduce_gate(const float* __restrict__ rps_partial,
    const int* __restrict__ route, float* __restrict__ rps, int* __restrict__ counts) {
  int e = blockIdx.x;
  float s = 0.f;
  int c = 0;
  for (int t = threadIdx.x; t < T_TOK; t += 256) {
    s += rps_partial[(size_t)t * 8 + e];
    c += (route[t] == e) ? 1 : 0;
  }
#pragma unroll
  for (int off = 32; off > 0; off >>= 1) {
    s += __shfl_down(s, off);
    c += __shfl_down(c, off);
  }
  __shared__ float sred[4];
  __shared__ int cred[4];
  int wid = threadIdx.x >> 6;
  if ((threadIdx.x & 63) == 0) { sred[wid] = s; cred[wid] = c; }
  __syncthreads();
  if (threadIdx.x == 0) {
    rps[e] = sred[0] + sred[1] + sred[2] + sred[3];
    counts[e] = cred[0] + cred[1] + cred[2] + cred[3];
  }
}

__global__ void init_kernel(int* cursor) {
  int i = threadIdx.x;
  if (i < E_EXP) cursor[i] = 0;
}

__global__ void offsets_kernel(const int* counts, int* offs, float* counts_f, float* ndrop) {
  if (threadIdx.x == 0) {
    int o = 0;
    for (int e = 0; e < E_EXP; e++) { offs[e] = o; o += counts[e]; }
    offs[E_EXP] = o;
    for (int e = 0; e < E_EXP; e++) counts_f[e] = (float)counts[e];
    *ndrop = 0.f;
  }
}

// ------- scatter with wave-aggregated atomics (<=512 atomics total) -------
__global__ void scatter_kernel(const int* __restrict__ route, const int* __restrict__ offs,
                               int* __restrict__ cursor, int* __restrict__ list) {
  int t = blockIdx.x * 256 + threadIdx.x;
  int lane = threadIdx.x & 63;
  int e = (t < T_TOK) ? route[t] : -1;
#pragma unroll
  for (int ex = 0; ex < E_EXP; ex++) {
    unsigned long long mask = __ballot(e == ex);
    int cntw = __popcll(mask);
    if (cntw) {
      int leader = __ffsll((unsigned long long)mask) - 1;
      int base = 0;
      if (lane == leader) base = atomicAdd(&cursor[ex], cntw);
      base = __shfl(base, leader);
      if (e == ex) {
        int rank = __popcll(mask & ((1ull << lane) - 1));
        list[offs[ex] + base + rank] = t;
      }
    }
  }
}

extern "C" void kernel_launch(void* const* d_in, const int* in_sizes, int n_in,
                              void* d_out, int out_size, void* d_ws, size_t ws_size,
                              hipStream_t stream) {
  const float* x = (const float*)d_in[0];
  const float* ln1_g = (const float*)d_in[1];
  const float* ln1_b = (const float*)d_in[2];
  const float* ln2_g = (const float*)d_in[3];
  const float* ln2_b = (const float*)d_in[4];
  const float* wq = (const float*)d_in[5];
  const float* bq = (const float*)d_in[6];
  const float* wk = (const float*)d_in[7];
  const float* bk = (const float*)d_in[8];
  const float* wv = (const float*)d_in[9];
  const float* bv = (const float*)d_in[10];
  const float* wo = (const float*)d_in[11];
  const float* bo = (const float*)d_in[12];
  const float* wg = (const float*)d_in[13];
  const float* bg = (const float*)d_in[14];
  const float* w1 = (const float*)d_in[15];
  const float* b1 = (const float*)d_in[16];
  const float* w2 = (const float*)d_in[17];
  const float* b2 = (const float*)d_in[18];

  float* out = (float*)d_out;
  float* counts_f = out + (size_t)T_TOK * D_DIM;
  float* rps = counts_f + E_EXP;
  float* ndrop = rps + E_EXP;
  float* pmax = ndrop + 1;

  const size_t MB1 = 1048576;
  char* base = (char*)d_ws;
  ush* zh  = (ush*)(base + 0 * MB1);
  ush* zl  = (ush*)(base + 8 * MB1);
  ush* qh  = (ush*)(base + 16 * MB1);
  ush* ql  = (ush*)(base + 24 * MB1);
  ush* kh  = (ush*)(base + 32 * MB1);
  ush* kl  = (ush*)(base + 40 * MB1);
  ush* vth = (ush*)(base + 48 * MB1);
  ush* vtl = (ush*)(base + 56 * MB1);
  ush* wT  = (ush*)(base + 64 * MB1);
  ush* oh  = (ush*)(base + 80 * MB1);
  ush* ol  = (ush*)(base + 88 * MB1);
  ush* zb  = (ush*)(base + 64 * MB1);
  ush* hb  = (ush*)(base + 72 * MB1);
  int* route  = (int*)(base + 104 * MB1);
  int* list   = route + T_TOK;
  int* counts = list + T_TOK;
  int* offs   = counts + E_EXP;
  int* cursor = offs + E_EXP + 1;
  float* rps_partial = (float*)(base + 106 * MB1);   // 4096*8*4 = 128 KB
  ush* w1t = (ush*)(base + 0 * MB1);
  ush* w2t = (ush*)(base + 112 * MB1);

  ln1_split<<<T_TOK, 256, 0, stream>>>(x, ln1_g, ln1_b, zh, zl);
  dim3 gt(32, 32);
  transpose_split<<<gt, 256, 0, stream>>>(wq, wT + 0 * 2097152, wT + 0 * 2097152 + 1048576, D_DIM, D_DIM);
  transpose_split<<<gt, 256, 0, stream>>>(wk, wT + 1 * 2097152, wT + 1 * 2097152 + 1048576, D_DIM, D_DIM);
  transpose_split<<<gt, 256, 0, stream>>>(wv, wT + 2 * 2097152, wT + 2 * 2097152 + 1048576, D_DIM, D_DIM);
  transpose_split<<<gt, 256, 0, stream>>>(wo, wT + 3 * 2097152, wT + 3 * 2097152 + 1048576, D_DIM, D_DIM);
  dim3 gq(32, 8, 3);
  qkv_mfma<<<gq, 256, 0, stream>>>(zh, zl, wT, bq, bk, bv, qh, kh, vth);
  dim3 ga(S_LEN / 128, B_SZ * H_HEADS);
  attn_mfma<<<ga, 256, 0, stream>>>(qh, ql, kh, kl, vth, vtl, oh, ol);
  dim3 gt1(F_DIM / 32, D_DIM / 32, E_EXP);
  transpose_bf16<<<gt1, 256, 0, stream>>>(w1, w1t, D_DIM, F_DIM);
  dim3 gt2(D_DIM / 32, F_DIM / 32, E_EXP);
  transpose_bf16<<<gt2, 256, 0, stream>>>(w2, w2t, F_DIM, D_DIM);
  dim3 gw(32, 8);
  wo_mfma<<<gw, 256, 0, stream>>>(oh, ol, wT + 3 * 2097152, bo, x, out);
  init_kernel<<<1, 64, 0, stream>>>(cursor);
  ln2_gate<<<T_TOK, 256, 0, stream>>>(out, ln2_g, ln2_b, wg, bg, zb, pmax, route, rps_partial);
  reduce_gate<<<E_EXP, 256, 0, stream>>>(rps_partial, route, rps, counts);
  offsets_kernel<<<1, 64, 0, stream>>>(counts, offs, counts_f, ndrop);
  scatter_kernel<<<16, 256, 0, stream>>>(route, offs, cursor, list);
  moe1_mfma<<<512, 256, 0, stream>>>(zb, w1t, b1, list, offs, hb);
  moe2_mfma<<<512, 256, 0, stream>>>(hb, w2t, b2, list, offs, pmax, out);
}

// Round 5
// 848.527 us; speedup vs baseline: 1.0446x; 1.0039x over previous
//
#include <hip/hip_runtime.h>

#define S_LEN 2048
#define B_SZ 2
#define D_DIM 1024
#define H_HEADS 16
#define DK_DIM 64
#define E_EXP 8
#define F_DIM 4096
#define T_TOK 4096   // S*B

typedef unsigned short ush;
typedef __bf16 bf16x8 __attribute__((ext_vector_type(8)));
typedef float f32x4 __attribute__((ext_vector_type(4)));

__device__ __forceinline__ ush f2bf(float f) {
  union { __bf16 h; ush u; } cv;
  cv.h = (__bf16)f;
  return cv.u;
}

__device__ __forceinline__ float bf2f(ush u) {
  union { unsigned int i; float f; } cv;
  cv.i = ((unsigned int)u) << 16;
  return cv.f;
}

// split v into hi + lo bf16 (v ~= hi + lo, rel err ~2^-17)
__device__ __forceinline__ void split2(float v, ush& h, ush& l) {
  ush hh = f2bf(v);
  h = hh;
  l = f2bf(v - bf2f(hh));
}

__device__ __forceinline__ void gload16(const void* g, void* l) {
  __builtin_amdgcn_global_load_lds(
      (const __attribute__((address_space(1))) unsigned int*)g,
      (__attribute__((address_space(3))) unsigned int*)l, 16, 0, 0);
}

#define MFMA(a, b, c) __builtin_amdgcn_mfma_f32_16x16x32_bf16(a, b, c, 0, 0, 0)

// ---- DPP 16-lane all-reduce (pure VALU, replaces ds_bpermute shuffles) ----
template <int CTRL>
__device__ __forceinline__ float dpp_mov(float x) {
  return __builtin_bit_cast(float,
      __builtin_amdgcn_update_dpp(0, __builtin_bit_cast(int, x), CTRL, 0xF, 0xF,
                                  true));
}
__device__ __forceinline__ float rmax16(float x) {
  x = fmaxf(x, dpp_mov<0xB1>(x));    // quad_perm xor1
  x = fmaxf(x, dpp_mov<0x4E>(x));    // quad_perm xor2
  x = fmaxf(x, dpp_mov<0x141>(x));   // row_half_mirror
  x = fmaxf(x, dpp_mov<0x140>(x));   // row_mirror
  return x;
}
__device__ __forceinline__ float rsum16(float x) {
  x += dpp_mov<0xB1>(x);
  x += dpp_mov<0x4E>(x);
  x += dpp_mov<0x141>(x);
  x += dpp_mov<0x140>(x);
  return x;
}

// ---------------- LN1: x -> split bf16 z ----------------
__global__ __launch_bounds__(256) void ln1_split(const float* __restrict__ x,
    const float* __restrict__ g, const float* __restrict__ b,
    ush* __restrict__ zh, ush* __restrict__ zl) {
  int t = blockIdx.x;
  float4 v = ((const float4*)(x + (size_t)t * D_DIM))[threadIdx.x];
  float s = v.x + v.y + v.z + v.w;
  float s2 = v.x * v.x + v.y * v.y + v.z * v.z + v.w * v.w;
#pragma unroll
  for (int off = 32; off > 0; off >>= 1) {
    s += __shfl_down(s, off);
    s2 += __shfl_down(s2, off);
  }
  __shared__ float red[8];
  int wid = threadIdx.x >> 6;
  if ((threadIdx.x & 63) == 0) { red[wid] = s; red[4 + wid] = s2; }
  __syncthreads();
  float sum = red[0] + red[1] + red[2] + red[3];
  float sq = red[4] + red[5] + red[6] + red[7];
  float mu = sum * (1.0f / D_DIM);
  float var = sq * (1.0f / D_DIM) - mu * mu;
  float rstd = rsqrtf(var + 1e-5f);
  float4 gg = ((const float4*)g)[threadIdx.x];
  float4 bb = ((const float4*)b)[threadIdx.x];
  float o[4];
  o[0] = (v.x - mu) * rstd * gg.x + bb.x;
  o[1] = (v.y - mu) * rstd * gg.y + bb.y;
  o[2] = (v.z - mu) * rstd * gg.z + bb.z;
  o[3] = (v.w - mu) * rstd * gg.w + bb.w;
  ushort4 uh, ul;
  split2(o[0], uh.x, ul.x); split2(o[1], uh.y, ul.y);
  split2(o[2], uh.z, ul.z); split2(o[3], uh.w, ul.w);
  *(ushort4*)(zh + (size_t)t * D_DIM + threadIdx.x * 4) = uh;
  *(ushort4*)(zl + (size_t)t * D_DIM + threadIdx.x * 4) = ul;
}

// ------------- transpose fp32 [R][C] -> split bf16 [C][R] -------------
__global__ __launch_bounds__(256) void transpose_split(const float* __restrict__ in,
    ush* __restrict__ outh, ush* __restrict__ outl, int R, int C) {
  __shared__ float tile[32][33];
  int c0 = blockIdx.x * 32, r0 = blockIdx.y * 32;
  int tx = threadIdx.x & 31, ty = threadIdx.x >> 5;
#pragma unroll
  for (int i = 0; i < 4; i++)
    tile[ty + i * 8][tx] = in[(size_t)(r0 + ty + i * 8) * C + c0 + tx];
  __syncthreads();
#pragma unroll
  for (int i = 0; i < 4; i++) {
    float v = tile[tx][ty + i * 8];
    ush h, l;
    split2(v, h, l);
    size_t idx = (size_t)(c0 + ty + i * 8) * R + r0 + tx;
    outh[idx] = h;
    outl[idx] = l;
  }
}

// ------------- transpose fp32 [E][R][C] -> plain bf16 [E][C][R] -------------
__global__ __launch_bounds__(256) void transpose_bf16(const float* __restrict__ in,
    ush* __restrict__ out, int R, int C) {
  __shared__ float tile[32][33];
  int e = blockIdx.z;
  const float* ip = in + (size_t)e * R * C;
  ush* op = out + (size_t)e * R * C;
  int c0 = blockIdx.x * 32, r0 = blockIdx.y * 32;
  int tx = threadIdx.x & 31, ty = threadIdx.x >> 5;
#pragma unroll
  for (int i = 0; i < 4; i++)
    tile[ty + i * 8][tx] = ip[(size_t)(r0 + ty + i * 8) * C + c0 + tx];
  __syncthreads();
#pragma unroll
  for (int i = 0; i < 4; i++)
    op[(size_t)(c0 + ty + i * 8) * R + r0 + tx] = f2bf(tile[tx][ty + i * 8]);
}

// ------- split-bf16 GEMM core: 128x128 tile, BK=64, XOR-swizzled LDS -------
__device__ __forceinline__ void split_gemm(const ush* __restrict__ Ah,
    const ush* __restrict__ Al, int lda, const ush* __restrict__ Bh,
    const ush* __restrict__ Bl, int ldb, int K, int tid, f32x4 acc[4][4],
    ush (*Ash)[64], ush (*Asl)[64], ush (*Bsh)[64], ush (*Bsl)[64]) {
  int lane = tid & 63, w = tid >> 6, quad = lane >> 4, ln15 = lane & 15;
  int srow = tid >> 3, pcol = (tid & 7) * 8;
  int scol = ((tid & 7) ^ (srow & 7)) * 8;   // swizzled global source chunk
  int sw = ln15 & 7;                         // frag-read swizzle key
  int mb = (w >> 1) * 64, nb = (w & 1) * 64;
  for (int kb = 0; kb < K; kb += 64) {
    __syncthreads();
#pragma unroll
    for (int r = 0; r < 4; r++) {
      int rr = r * 32 + srow;
      gload16(Ah + (size_t)rr * lda + kb + scol, &Ash[rr][pcol]);
      gload16(Al + (size_t)rr * lda + kb + scol, &Asl[rr][pcol]);
      gload16(Bh + (size_t)rr * ldb + kb + scol, &Bsh[rr][pcol]);
      gload16(Bl + (size_t)rr * ldb + kb + scol, &Bsl[rr][pcol]);
    }
    __syncthreads();
#pragma unroll
    for (int kc = 0; kc < 2; kc++) {
      int kof = ((kc * 4 + quad) ^ sw) * 8;
      bf16x8 avh[4], avl[4], bvh[4], bvl[4];
#pragma unroll
      for (int i = 0; i < 4; i++) {
        avh[i] = *(const bf16x8*)&Ash[mb + i * 16 + ln15][kof];
        avl[i] = *(const bf16x8*)&Asl[mb + i * 16 + ln15][kof];
        bvh[i] = *(const bf16x8*)&Bsh[nb + i * 16 + ln15][kof];
        bvl[i] = *(const bf16x8*)&Bsl[nb + i * 16 + ln15][kof];
      }
#pragma unroll
      for (int mi = 0; mi < 4; mi++)
#pragma unroll
        for (int ni = 0; ni < 4; ni++) {
          acc[mi][ni] = MFMA(avh[mi], bvh[ni], acc[mi][ni]);
          acc[mi][ni] = MFMA(avh[mi], bvl[ni], acc[mi][ni]);
          acc[mi][ni] = MFMA(avl[mi], bvh[ni], acc[mi][ni]);
        }
    }
  }
}

// ---------------- QKV: z @ w{q,k,v} + bias -> split bf16 ----------------
__global__ __launch_bounds__(256) void qkv_mfma(const ush* __restrict__ zh,
    const ush* __restrict__ zl, const ush* __restrict__ wT,
    const float* __restrict__ bq, const float* __restrict__ bk,
    const float* __restrict__ bv, ush* __restrict__ qh_, ush* __restrict__ kh_,
    ush* __restrict__ vth_) {
  __shared__ ush Ash[128][64], Asl[128][64], Bsh[128][64], Bsl[128][64];
  int z = blockIdx.z;
  int m0 = blockIdx.x * 128, n0 = blockIdx.y * 128;
  const ush* Bh = wT + (size_t)z * 2097152;
  const ush* Bl = Bh + 1048576;
  const float* bias = (z == 0) ? bq : (z == 1) ? bk : bv;
  ush* outh = (z == 0) ? qh_ : (z == 1) ? kh_ : vth_;
  int tid = threadIdx.x, lane = tid & 63, w = tid >> 6;
  int quad = lane >> 4, ln15 = lane & 15;
  int mb = (w >> 1) * 64, nb = (w & 1) * 64;
  f32x4 acc[4][4] = {};
  split_gemm(zh + (size_t)m0 * D_DIM, zl + (size_t)m0 * D_DIM, D_DIM,
             Bh + (size_t)n0 * D_DIM, Bl + (size_t)n0 * D_DIM, D_DIM, D_DIM,
             tid, acc, Ash, Asl, Bsh, Bsl);
#pragma unroll
  for (int mi = 0; mi < 4; mi++)
#pragma unroll
    for (int reg = 0; reg < 4; reg++) {
      int m = m0 + mb + mi * 16 + quad * 4 + reg;
      int s = m >> 1, b = m & 1;
#pragma unroll
      for (int ni = 0; ni < 4; ni++) {
        int n = n0 + nb + ni * 16 + ln15;
        float val = acc[mi][ni][reg] + bias[n];
        ush hh, ll;
        split2(val, hh, ll);
        int h = n >> 6, dk = n & 63;
        size_t idx;
        if (z < 2) idx = ((size_t)(b * H_HEADS + h) * S_LEN + s) * DK_DIM + dk;
        else       idx = ((size_t)(b * H_HEADS + h) * DK_DIM + dk) * S_LEN + s;
        outh[idx] = hh;
        outh[idx + 4194304] = ll;   // lo buffer is +8 MB after hi
      }
    }
}

// ---------------- Flash attention v3 (unchanged) ----------------
__global__ __launch_bounds__(256, 2) void attn_mfma(const ush* __restrict__ qh,
    const ush* __restrict__ ql, const ush* __restrict__ kh,
    const ush* __restrict__ kl, const ush* __restrict__ vth,
    const ush* __restrict__ vtl, ush* __restrict__ oh, ush* __restrict__ ol) {
  int bh = blockIdx.y, q0 = blockIdx.x * 128;
  const size_t hoff = (size_t)bh * S_LEN * DK_DIM;
  __shared__ float4 smemv[3072];       // 48 KB
  ush* Ph_ = (ush*)smemv;              // [128][64] bf16 P (wave-private rows)
  ush* Kh_ = (ush*)smemv + 8192;       // [64][64]
  ush* Kl_ = (ush*)smemv + 12288;
  ush* Vh_ = (ush*)smemv + 16384;      // [64][64] (Vt: row=dk, col=key)
  ush* Vl_ = (ush*)smemv + 20480;
  int tid = threadIdx.x, lane = tid & 63, w = tid >> 6;
  int quad = lane >> 4, ln15 = lane & 15;
  int srow = tid >> 3;                 // staging row 0..31
  int schunk = tid & 7;                // LDS dst chunk (fixed by gload16)
  int gch = (schunk ^ (srow & 7)) * 8; // swizzled global source chunk (ush)
  int sw = ln15 & 7;                   // frag-read swizzle key
  // ---- prologue: issue K-tile 0 loads; Q fragments direct from global ----
#pragma unroll
  for (int p = 0; p < 2; p++) {
    int r = p * 32 + srow;
    gload16(kh + hoff + (size_t)r * DK_DIM + gch, Kh_ + r * 64 + schunk * 8);
    gload16(kl + hoff + (size_t)r * DK_DIM + gch, Kl_ + r * 64 + schunk * 8);
  }
  bf16x8 Qf[2][2][2];   // [mi][kc][hi/lo]
#pragma unroll
  for (int mi = 0; mi < 2; mi++)
#pragma unroll
    for (int kc = 0; kc < 2; kc++) {
      size_t qidx = hoff + (size_t)(q0 + w * 32 + mi * 16 + ln15) * DK_DIM +
                    (kc * 4 + quad) * 8;
      Qf[mi][kc][0] = *(const bf16x8*)(qh + qidx);
      Qf[mi][kc][1] = *(const bf16x8*)(ql + qidx);
    }
  f32x4 Oacc[2][4] = {};
  float m_i[2][4], l_i[2][4];
#pragma unroll
  for (int mi = 0; mi < 2; mi++)
#pragma unroll
    for (int r = 0; r < 4; r++) { m_i[mi][r] = -3e38f; l_i[mi][r] = 0.f; }
  const float cs = 0.18033688f;        // 0.125 * log2(e): exp2-domain softmax
  __syncthreads();                     // K0 landed
  for (int kt = 0; kt < S_LEN / 64; kt++) {
    // ---- phase A: issue V(kt) loads; QK^T; softmax; store P ----
#pragma unroll
    for (int p = 0; p < 2; p++) {
      int r = p * 32 + srow;
      gload16(vth + hoff + (size_t)r * S_LEN + kt * 64 + gch,
              Vh_ + r * 64 + schunk * 8);
      gload16(vtl + hoff + (size_t)r * S_LEN + kt * 64 + gch,
              Vl_ + r * 64 + schunk * 8);
    }
    f32x4 S[2][4] = {};
#pragma unroll
    for (int kc = 0; kc < 2; kc++) {
      int ch = ((kc * 4 + quad) ^ sw) * 8;
      bf16x8 bkh[4], bkl[4];
#pragma unroll
      for (int ni = 0; ni < 4; ni++) {
        int row = ni * 16 + ln15;
        bkh[ni] = *(const bf16x8*)(Kh_ + row * 64 + ch);
        bkl[ni] = *(const bf16x8*)(Kl_ + row * 64 + ch);
      }
      __builtin_amdgcn_s_setprio(1);
#pragma unroll
      for (int mi = 0; mi < 2; mi++)
#pragma unroll
        for (int ni = 0; ni < 4; ni++) {
          S[mi][ni] = MFMA(Qf[mi][kc][0], bkh[ni], S[mi][ni]);
          S[mi][ni] = MFMA(Qf[mi][kc][0], bkl[ni], S[mi][ni]);
          S[mi][ni] = MFMA(Qf[mi][kc][1], bkh[ni], S[mi][ni]);
        }
      __builtin_amdgcn_s_setprio(0);
    }
    // ---- online softmax: row max via DPP (raw units) ----
    float mt[2][4];
#pragma unroll
    for (int mi = 0; mi < 2; mi++)
#pragma unroll
      for (int reg = 0; reg < 4; reg++) {
        float m = fmaxf(fmaxf(S[mi][0][reg], S[mi][1][reg]),
                        fmaxf(S[mi][2][reg], S[mi][3][reg]));
        mt[mi][reg] = rmax16(m);
      }
    // ---- deferred-max rescale (T13) ----
    float growth = -3e38f;
#pragma unroll
    for (int mi = 0; mi < 2; mi++)
#pragma unroll
      for (int reg = 0; reg < 4; reg++)
        growth = fmaxf(growth, mt[mi][reg] - m_i[mi][reg]);
    if (__any(growth > 44.3614195f)) {   // 8 / cs  =>  p bounded by 2^8
#pragma unroll
      for (int mi = 0; mi < 2; mi++)
#pragma unroll
        for (int reg = 0; reg < 4; reg++) {
          float mnew = fmaxf(m_i[mi][reg], mt[mi][reg]);
          float a = __builtin_amdgcn_exp2f(cs * (m_i[mi][reg] - mnew));
          m_i[mi][reg] = mnew;
          l_i[mi][reg] *= a;
#pragma unroll
          for (int ni = 0; ni < 4; ni++) Oacc[mi][ni][reg] *= a;
        }
    }
    float ncm[2][4], ls[2][4] = {};
#pragma unroll
    for (int mi = 0; mi < 2; mi++)
#pragma unroll
      for (int reg = 0; reg < 4; reg++) ncm[mi][reg] = cs * m_i[mi][reg];
#pragma unroll
    for (int mi = 0; mi < 2; mi++)
#pragma unroll
      for (int ni = 0; ni < 4; ni++)
#pragma unroll
        for (int reg = 0; reg < 4; reg++) {
          float p = __builtin_amdgcn_exp2f(
              fmaf(S[mi][ni][reg], cs, -ncm[mi][reg]));
          ush hh = f2bf(p);
          ls[mi][reg] += bf2f(hh);   // sum the ROUNDED p: matches PV numerator
          int row = w * 32 + mi * 16 + quad * 4 + reg;
          int cph = ((ni * 2 + (ln15 >> 3)) ^ ((quad * 4 + reg) & 7)) * 8 + (ln15 & 7);
          Ph_[row * 64 + cph] = hh;
        }
#pragma unroll
    for (int mi = 0; mi < 2; mi++)
#pragma unroll
      for (int reg = 0; reg < 4; reg++)
        l_i[mi][reg] += rsum16(ls[mi][reg]);
    __syncthreads();                 // V landed; all waves done reading K
    // ---- phase B: issue K(kt+1) loads; O += P @ V ----
    if (kt + 1 < S_LEN / 64) {
#pragma unroll
      for (int p = 0; p < 2; p++) {
        int r = p * 32 + srow;
        gload16(kh + hoff + (size_t)((kt + 1) * 64 + r) * DK_DIM + gch,
                Kh_ + r * 64 + schunk * 8);
        gload16(kl + hoff + (size_t)((kt + 1) * 64 + r) * DK_DIM + gch,
                Kl_ + r * 64 + schunk * 8);
      }
    }
#pragma unroll
    for (int kc = 0; kc < 2; kc++) {
      int ch = ((kc * 4 + quad) ^ sw) * 8;
      bf16x8 ap[2], bvh[4], bvl[4];
#pragma unroll
      for (int mi = 0; mi < 2; mi++) {
        int row = w * 32 + mi * 16 + ln15;
        ap[mi] = *(const bf16x8*)(Ph_ + row * 64 + ch);
      }
#pragma unroll
      for (int ni = 0; ni < 4; ni++) {
        int row = ni * 16 + ln15;
        bvh[ni] = *(const bf16x8*)(Vh_ + row * 64 + ch);
        bvl[ni] = *(const bf16x8*)(Vl_ + row * 64 + ch);
      }
      __builtin_amdgcn_s_setprio(1);
#pragma unroll
      for (int mi = 0; mi < 2; mi++)
#pragma unroll
        for (int ni = 0; ni < 4; ni++) {
          Oacc[mi][ni] = MFMA(ap[mi], bvh[ni], Oacc[mi][ni]);
          Oacc[mi][ni] = MFMA(ap[mi], bvl[ni], Oacc[mi][ni]);
        }
      __builtin_amdgcn_s_setprio(0);
    }
    __syncthreads();                 // K(kt+1) landed; all waves done with V/P
  }
  // ---- epilogue ----
  float inv[2][4];
#pragma unroll
  for (int mi = 0; mi < 2; mi++)
#pragma unroll
    for (int reg = 0; reg < 4; reg++) inv[mi][reg] = 1.0f / l_i[mi][reg];
  int b = bh >> 4, h = bh & 15;
#pragma unroll
  for (int mi = 0; mi < 2; mi++)
#pragma unroll
    for (int ni = 0; ni < 4; ni++)
#pragma unroll
      for (int reg = 0; reg < 4; reg++) {
        float ov = Oacc[mi][ni][reg] * inv[mi][reg];
        int s = q0 + w * 32 + mi * 16 + quad * 4 + reg;
        int col = h * DK_DIM + ni * 16 + ln15;
        size_t idx = (size_t)(s * B_SZ + b) * D_DIM + col;
        ush hh, ll;
        split2(ov, hh, ll);
        oh[idx] = hh;
        ol[idx] = ll;
      }
}

// ---------------- Wo: out = x + o @ wo + bo (fp32 out) ----------------
__global__ __launch_bounds__(256) void wo_mfma(const ush* __restrict__ oh,
    const ush* __restrict__ ol, const ush* __restrict__ woTh,
    const float* __restrict__ bo, const float* __restrict__ x,
    float* __restrict__ out) {
  __shared__ ush Ash[128][64], Asl[128][64], Bsh[128][64], Bsl[128][64];
  int m0 = blockIdx.x * 128, n0 = blockIdx.y * 128;
  const ush* Bl = woTh + 1048576;
  int tid = threadIdx.x, lane = tid & 63, w = tid >> 6;
  int quad = lane >> 4, ln15 = lane & 15;
  int mb = (w >> 1) * 64, nb = (w & 1) * 64;
  f32x4 acc[4][4] = {};
  split_gemm(oh + (size_t)m0 * D_DIM, ol + (size_t)m0 * D_DIM, D_DIM,
             woTh + (size_t)n0 * D_DIM, Bl + (size_t)n0 * D_DIM, D_DIM, D_DIM,
             tid, acc, Ash, Asl, Bsh, Bsl);
#pragma unroll
  for (int mi = 0; mi < 4; mi++)
#pragma unroll
    for (int reg = 0; reg < 4; reg++) {
      int m = m0 + mb + mi * 16 + quad * 4 + reg;
#pragma unroll
      for (int ni = 0; ni < 4; ni++) {
        int n = n0 + nb + ni * 16 + ln15;
        size_t idx = (size_t)m * D_DIM + n;
        out[idx] = x[idx] + acc[mi][ni][reg] + bo[n];
      }
    }
}

// ------- MoE GEMM1: counted-vmcnt double-buffer pipeline (T3+T4) -------
// Raw s_barrier + s_waitcnt vmcnt(8): tile t+1's 8 loads stay in flight
// across the barrier while tile t computes. grid 512 = 2 blk/CU (grid-capped,
// so 64KB LDS costs nothing). XOR swizzle + XCD expert locality kept.
__global__ __launch_bounds__(256) void moe1_mfma(const ush* __restrict__ zb,
    const ush* __restrict__ w1t, const float* __restrict__ b1,
    const int* __restrict__ list, const int* __restrict__ offs,
    ush* __restrict__ h) {
  int id = blockIdx.x;
  int e = id & 7;
  int mhalf = (id >> 3) & 1;
  int n0 = ((id >> 4) & 31) * 128;
  int off = offs[e], cnt = offs[e + 1] - off;
  __shared__ ush As[2][128][64], Bs[2][128][64];   // 64 KB
  int tid = threadIdx.x, lane = tid & 63, w = tid >> 6;
  int srw = w * 8 + (lane >> 3);                 // staging row 0..31
  int colb = (lane & 7) * 8;                     // linear LDS dst chunk
  int scol = ((lane & 7) ^ (srw & 7)) * 8;       // swizzled global src chunk
  int mb = (w >> 1) * 64, nb = (w & 1) * 64;
  int quad = lane >> 4, ln15 = lane & 15, sw = ln15 & 7;
  const ush* gB[4];
#pragma unroll
  for (int r = 0; r < 4; r++)
    gB[r] = w1t + ((size_t)e * F_DIM + n0 + r * 32 + srw) * D_DIM + scol;
  const float* be = b1 + (size_t)e * F_DIM;
  for (int m0 = mhalf * 128; m0 < cnt; m0 += 256) {
    const ush* gA[4];
#pragma unroll
    for (int r = 0; r < 4; r++) {
      int ra = m0 + r * 32 + srw; if (ra > cnt - 1) ra = cnt - 1;
      gA[r] = zb + (size_t)list[off + ra] * D_DIM + scol;
    }
#define STG1(buf, kb) do { _Pragma("unroll")                                   \
    for (int r = 0; r < 4; r++) {                                              \
      gload16(gA[r] + (kb), &As[buf][r * 32 + srw][colb]);                     \
      gload16(gB[r] + (kb), &Bs[buf][r * 32 + srw][colb]); } } while (0)
    STG1(0, 0);                        // prologue: tile 0 in flight
    f32x4 acc[4][4] = {};
    for (int ki = 0; ki < 16; ki++) {
      int cur = ki & 1;
      if (ki < 15) {
        STG1(cur ^ 1, (ki + 1) * 64);  // issue next tile BEFORE compute
        asm volatile("s_waitcnt vmcnt(8)" ::: "memory");  // tile ki done;
      } else {                                            // ki+1's 8 in flight
        asm volatile("s_waitcnt vmcnt(0)" ::: "memory");
      }
      __builtin_amdgcn_s_barrier();    // all waves: buf[cur] fully loaded
#pragma unroll
      for (int kc = 0; kc < 2; kc++) {
        int kof = ((kc * 4 + quad) ^ sw) * 8;
        bf16x8 av[4], bv[4];
#pragma unroll
        for (int i = 0; i < 4; i++) {
          av[i] = *(const bf16x8*)&As[cur][mb + i * 16 + ln15][kof];
          bv[i] = *(const bf16x8*)&Bs[cur][nb + i * 16 + ln15][kof];
        }
        __builtin_amdgcn_s_setprio(1);
#pragma unroll
        for (int mi = 0; mi < 4; mi++)
#pragma unroll
          for (int ni = 0; ni < 4; ni++)
            acc[mi][ni] = MFMA(av[mi], bv[ni], acc[mi][ni]);
        __builtin_amdgcn_s_setprio(0);
      }
      __builtin_amdgcn_s_barrier();    // all waves done reading buf[cur]
    }
#undef STG1
#pragma unroll
    for (int mi = 0; mi < 4; mi++)
#pragma unroll
      for (int reg = 0; reg < 4; reg++) {
        int lm = m0 + mb + mi * 16 + quad * 4 + reg;
        if (lm < cnt) {
#pragma unroll
          for (int ni = 0; ni < 4; ni++) {
            int n = n0 + nb + ni * 16 + ln15;
            float v = acc[mi][ni][reg] + be[n];
            h[(size_t)(off + lm) * F_DIM + n] = f2bf(fmaxf(v, 0.f));
          }
        }
      }
  }
}

// ------- MoE GEMM2: counted-vmcnt double-buffer pipeline; splitK=4 -------
__global__ __launch_bounds__(256) void moe2_mfma(const ush* __restrict__ hb,
    const ush* __restrict__ w2t, const float* __restrict__ b2,
    const int* __restrict__ list, const int* __restrict__ offs,
    const float* __restrict__ pmax, float* __restrict__ out) {
  int id = blockIdx.x;
  int e = id & 7;
  int mhalf = (id >> 3) & 1;
  int n0 = ((id >> 4) & 7) * 128;
  int ks = (id >> 7) & 3;
  int off = offs[e], cnt = offs[e + 1] - off;
  size_t kbase = (size_t)ks * 1024;
  __shared__ ush As[2][128][64], Bs[2][128][64];   // 64 KB
  int tid = threadIdx.x, lane = tid & 63, w = tid >> 6;
  int srw = w * 8 + (lane >> 3);
  int colb = (lane & 7) * 8;
  int scol = ((lane & 7) ^ (srw & 7)) * 8;
  int mb = (w >> 1) * 64, nb = (w & 1) * 64;
  int quad = lane >> 4, ln15 = lane & 15, sw = ln15 & 7;
  const ush* gB[4];
#pragma unroll
  for (int r = 0; r < 4; r++)
    gB[r] = w2t + ((size_t)e * D_DIM + n0 + r * 32 + srw) * F_DIM + kbase + scol;
  const float* be = b2 + (size_t)e * D_DIM;
  for (int m0 = mhalf * 128; m0 < cnt; m0 += 256) {
    const ush* gA[4];
#pragma unroll
    for (int r = 0; r < 4; r++) {
      int ra = m0 + r * 32 + srw; if (ra > cnt - 1) ra = cnt - 1;
      gA[r] = hb + (size_t)(off + ra) * F_DIM + kbase + scol;
    }
#define STG2(buf, kb) do { _Pragma("unroll")                                   \
    for (int r = 0; r < 4; r++) {                                              \
      gload16(gA[r] + (kb), &As[buf][r * 32 + srw][colb]);                     \
      gload16(gB[r] + (kb), &Bs[buf][r * 32 + srw][colb]); } } while (0)
    STG2(0, 0);                        // prologue: tile 0 in flight
    f32x4 acc[4][4] = {};
    for (int ki = 0; ki < 16; ki++) {
      int cur = ki & 1;
      if (ki < 15) {
        STG2(cur ^ 1, (ki + 1) * 64);  // issue next tile BEFORE compute
        asm volatile("s_waitcnt vmcnt(8)" ::: "memory");
      } else {
        asm volatile("s_waitcnt vmcnt(0)" ::: "memory");
      }
      __builtin_amdgcn_s_barrier();    // all waves: buf[cur] fully loaded
#pragma unroll
      for (int kc = 0; kc < 2; kc++) {
        int kof = ((kc * 4 + quad) ^ sw) * 8;
        bf16x8 av[4], bv[4];
#pragma unroll
        for (int i = 0; i < 4; i++) {
          av[i] = *(const bf16x8*)&As[cur][mb + i * 16 + ln15][kof];
          bv[i] = *(const bf16x8*)&Bs[cur][nb + i * 16 + ln15][kof];
        }
        __builtin_amdgcn_s_setprio(1);
#pragma unroll
        for (int mi = 0; mi < 4; mi++)
#pragma unroll
          for (int ni = 0; ni < 4; ni++)
            acc[mi][ni] = MFMA(av[mi], bv[ni], acc[mi][ni]);
        __builtin_amdgcn_s_setprio(0);
      }
      __builtin_amdgcn_s_barrier();    // all waves done reading buf[cur]
    }
#undef STG2
#pragma unroll
    for (int mi = 0; mi < 4; mi++)
#pragma unroll
      for (int reg = 0; reg < 4; reg++) {
        int lm = m0 + mb + mi * 16 + quad * 4 + reg;
        if (lm < cnt) {
          int tok = list[off + lm];
          float p = pmax[tok];
#pragma unroll
          for (int ni = 0; ni < 4; ni++) {
            int n = n0 + nb + ni * 16 + ln15;
            float v = acc[mi][ni][reg];
            if (ks == 0) v += be[n];
            atomicAdd(&out[(size_t)tok * D_DIM + n], v * p);
          }
        }
      }
  }
}

// ------- LN2 + gate fused: NO global atomics; per-token partials -------
__global__ __launch_bounds__(256) void ln2_gate(const float* __restrict__ x,
    const float* __restrict__ g, const float* __restrict__ b,
    const float* __restrict__ wg, const float* __restrict__ bg,
    ush* __restrict__ zb, float* __restrict__ pmax_out, int* __restrict__ route,
    float* __restrict__ rps_partial) {
  int t = blockIdx.x;
  float4 v = ((const float4*)(x + (size_t)t * D_DIM))[threadIdx.x];
  float s = v.x + v.y + v.z + v.w;
  float s2 = v.x * v.x + v.y * v.y + v.z * v.z + v.w * v.w;
#pragma unroll
  for (int off = 32; off > 0; off >>= 1) {
    s += __shfl_down(s, off);
    s2 += __shfl_down(s2, off);
  }
  __shared__ float red[8];
  int wid = threadIdx.x >> 6;
  if ((threadIdx.x & 63) == 0) { red[wid] = s; red[4 + wid] = s2; }
  __syncthreads();
  float sum = red[0] + red[1] + red[2] + red[3];
  float sq = red[4] + red[5] + red[6] + red[7];
  float mu = sum * (1.0f / D_DIM);
  float var = sq * (1.0f / D_DIM) - mu * mu;
  float rstd = rsqrtf(var + 1e-5f);
  float4 gg = ((const float4*)g)[threadIdx.x];
  float4 bb = ((const float4*)b)[threadIdx.x];
  float zz[4];
  zz[0] = (v.x - mu) * rstd * gg.x + bb.x;
  zz[1] = (v.y - mu) * rstd * gg.y + bb.y;
  zz[2] = (v.z - mu) * rstd * gg.z + bb.z;
  zz[3] = (v.w - mu) * rstd * gg.w + bb.w;
  ushort4 u;
  u.x = f2bf(zz[0]); u.y = f2bf(zz[1]); u.z = f2bf(zz[2]); u.w = f2bf(zz[3]);
  *(ushort4*)(zb + (size_t)t * D_DIM + threadIdx.x * 4) = u;
  int d0 = threadIdx.x * 4;
  float acc[8] = {};
  const float* w0 = wg + (size_t)d0 * E_EXP;
#pragma unroll
  for (int i = 0; i < 4; i++)
#pragma unroll
    for (int e = 0; e < 8; e++)
      acc[e] += zz[i] * w0[i * 8 + e];
#pragma unroll
  for (int off = 32; off > 0; off >>= 1)
#pragma unroll
    for (int e = 0; e < 8; e++) acc[e] += __shfl_down(acc[e], off);
  __shared__ float red2[4][8];
  if ((threadIdx.x & 63) == 0)
#pragma unroll
    for (int e = 0; e < 8; e++) red2[threadIdx.x >> 6][e] = acc[e];
  __syncthreads();
  if (threadIdx.x == 0) {
    float lg[8];
#pragma unroll
    for (int e = 0; e < 8; e++)
      lg[e] = red2[0][e] + red2[1][e] + red2[2][e] + red2[3][e] + bg[e];
    float mx = lg[0];
    int am = 0;
#pragma unroll
    for (int e = 1; e < 8; e++)
      if (lg[e] > mx) { mx = lg[e]; am = e; }
    float se = 0.f, pe[8];
#pragma unroll
    for (int e = 0; e < 8; e++) { pe[e] = expf(lg[e] - mx); se += pe[e]; }
    float inv = 1.0f / se;
    pmax_out[t] = inv;
    route[t] = am;
#pragma unroll
    for (int e = 0; e < 8; e++) rps_partial[(size_t)t * 8 + e] = pe[e] * inv;
  }
}

// ------- reduce partials: rps[e] = sum_t partial[t][e]; counts[e] -------
__global__ __launch_bounds__(256) void reduce_gate(const float* __restrict__ rps_partial,
    const int* __restrict__ route, float* __restrict__ rps, int* __restrict__ counts) {
  int e = blockIdx.x;
  float s = 0.f;
  int c = 0;
  for (int t = threadIdx.x; t < T_TOK; t += 256) {
    s += rps_partial[(size_t)t * 8 + e];
    c += (route[t] == e) ? 1 : 0;
  }
#pragma unroll
  for (int off = 32; off > 0; off >>= 1) {
    s += __shfl_down(s, off);
    c += __shfl_down(c, off);
  }
  __shared__ float sred[4];
  __shared__ int cred[4];
  int wid = threadIdx.x >> 6;
  if ((threadIdx.x & 63) == 0) { sred[wid] = s; cred[wid] = c; }
  __syncthreads();
  if (threadIdx.x == 0) {
    rps[e] = sred[0] + sred[1] + sred[2] + sred[3];
    counts[e] = cred[0] + cred[1] + cred[2] + cred[3];
  }
}

__global__ void init_kernel(int* cursor) {
  int i = threadIdx.x;
  if (i < E_EXP) cursor[i] = 0;
}

__global__ void offsets_kernel(const int* counts, int* offs, float* counts_f, float* ndrop) {
  if (threadIdx.x == 0) {
    int o = 0;
    for (int e = 0; e < E_EXP; e++) { offs[e] = o; o += counts[e]; }
    offs[E_EXP] = o;
    for (int e = 0; e < E_EXP; e++) counts_f[e] = (float)counts[e];
    *ndrop = 0.f;
  }
}

// ------- scatter with wave-aggregated atomics (<=512 atomics total) -------
__global__ void scatter_kernel(const int* __restrict__ route, const int* __restrict__ offs,
                               int* __restrict__ cursor, int* __restrict__ list) {
  int t = blockIdx.x * 256 + threadIdx.x;
  int lane = threadIdx.x & 63;
  int e = (t < T_TOK) ? route[t] : -1;
#pragma unroll
  for (int ex = 0; ex < E_EXP; ex++) {
    unsigned long long mask = __ballot(e == ex);
    int cntw = __popcll(mask);
    if (cntw) {
      int leader = __ffsll((unsigned long long)mask) - 1;
      int base = 0;
      if (lane == leader) base = atomicAdd(&cursor[ex], cntw);
      base = __shfl(base, leader);
      if (e == ex) {
        int rank = __popcll(mask & ((1ull << lane) - 1));
        list[offs[ex] + base + rank] = t;
      }
    }
  }
}

extern "C" void kernel_launch(void* const* d_in, const int* in_sizes, int n_in,
                              void* d_out, int out_size, void* d_ws, size_t ws_size,
                              hipStream_t stream) {
  const float* x = (const float*)d_in[0];
  const float* ln1_g = (const float*)d_in[1];
  const float* ln1_b = (const float*)d_in[2];
  const float* ln2_g = (const float*)d_in[3];
  const float* ln2_b = (const float*)d_in[4];
  const float* wq = (const float*)d_in[5];
  const float* bq = (const float*)d_in[6];
  const float* wk = (const float*)d_in[7];
  const float* bk = (const float*)d_in[8];
  const float* wv = (const float*)d_in[9];
  const float* bv = (const float*)d_in[10];
  const float* wo = (const float*)d_in[11];
  const float* bo = (const float*)d_in[12];
  const float* wg = (const float*)d_in[13];
  const float* bg = (const float*)d_in[14];
  const float* w1 = (const float*)d_in[15];
  const float* b1 = (const float*)d_in[16];
  const float* w2 = (const float*)d_in[17];
  const float* b2 = (const float*)d_in[18];

  float* out = (float*)d_out;
  float* counts_f = out + (size_t)T_TOK * D_DIM;
  float* rps = counts_f + E_EXP;
  float* ndrop = rps + E_EXP;
  float* pmax = ndrop + 1;

  const size_t MB1 = 1048576;
  char* base = (char*)d_ws;
  ush* zh  = (ush*)(base + 0 * MB1);
  ush* zl  = (ush*)(base + 8 * MB1);
  ush* qh  = (ush*)(base + 16 * MB1);
  ush* ql  = (ush*)(base + 24 * MB1);
  ush* kh  = (ush*)(base + 32 * MB1);
  ush* kl  = (ush*)(base + 40 * MB1);
  ush* vth = (ush*)(base + 48 * MB1);
  ush* vtl = (ush*)(base + 56 * MB1);
  ush* wT  = (ush*)(base + 64 * MB1);
  ush* oh  = (ush*)(base + 80 * MB1);
  ush* ol  = (ush*)(base + 88 * MB1);
  ush* zb  = (ush*)(base + 64 * MB1);
  ush* hb  = (ush*)(base + 72 * MB1);
  int* route  = (int*)(base + 104 * MB1);
  int* list   = route + T_TOK;
  int* counts = list + T_TOK;
  int* offs   = counts + E_EXP;
  int* cursor = offs + E_EXP + 1;
  float* rps_partial = (float*)(base + 106 * MB1);   // 4096*8*4 = 128 KB
  ush* w1t = (ush*)(base + 0 * MB1);
  ush* w2t = (ush*)(base + 112 * MB1);

  ln1_split<<<T_TOK, 256, 0, stream>>>(x, ln1_g, ln1_b, zh, zl);
  dim3 gt(32, 32);
  transpose_split<<<gt, 256, 0, stream>>>(wq, wT + 0 * 2097152, wT + 0 * 2097152 + 1048576, D_DIM, D_DIM);
  transpose_split<<<gt, 256, 0, stream>>>(wk, wT + 1 * 2097152, wT + 1 * 2097152 + 1048576, D_DIM, D_DIM);
  transpose_split<<<gt, 256, 0, stream>>>(wv, wT + 2 * 2097152, wT + 2 * 2097152 + 1048576, D_DIM, D_DIM);
  transpose_split<<<gt, 256, 0, stream>>>(wo, wT + 3 * 2097152, wT + 3 * 2097152 + 1048576, D_DIM, D_DIM);
  dim3 gq(32, 8, 3);
  qkv_mfma<<<gq, 256, 0, stream>>>(zh, zl, wT, bq, bk, bv, qh, kh, vth);
  dim3 ga(S_LEN / 128, B_SZ * H_HEADS);
  attn_mfma<<<ga, 256, 0, stream>>>(qh, ql, kh, kl, vth, vtl, oh, ol);
  dim3 gt1(F_DIM / 32, D_DIM / 32, E_EXP);
  transpose_bf16<<<gt1, 256, 0, stream>>>(w1, w1t, D_DIM, F_DIM);
  dim3 gt2(D_DIM / 32, F_DIM / 32, E_EXP);
  transpose_bf16<<<gt2, 256, 0, stream>>>(w2, w2t, F_DIM, D_DIM);
  dim3 gw(32, 8);
  wo_mfma<<<gw, 256, 0, stream>>>(oh, ol, wT + 3 * 2097152, bo, x, out);
  init_kernel<<<1, 64, 0, stream>>>(cursor);
  ln2_gate<<<T_TOK, 256, 0, stream>>>(out, ln2_g, ln2_b, wg, bg, zb, pmax, route, rps_partial);
  reduce_gate<<<E_EXP, 256, 0, stream>>>(rps_partial, route, rps, counts);
  offsets_kernel<<<1, 64, 0, stream>>>(counts, offs, counts_f, ndrop);
  scatter_kernel<<<16, 256, 0, stream>>>(route, offs, cursor, list);
  moe1_mfma<<<512, 256, 0, stream>>>(zb, w1t, b1, list, offs, hb);
  moe2_mfma<<<512, 256, 0, stream>>>(hb, w2t, b2, list, offs, pmax, out);
}